// Round 6
// baseline (1952.898 us; speedup 1.0000x reference)
//
#include <hip/hip_runtime.h>
#include <hip/hip_fp16.h>

// StackedAttentionModel: 8-layer transformer fwd, S=2048 E=1024 H=16 D=64 F=4096 V=32000.
// fp16 MFMA (fp32 accum), global activation scale CS=2^12 folded out exactly.
// R6: revert GEMMs to R3 schedule (bulk reads, counted vmcnt, 2 barriers/tile = best measured);
//     within-probe A/B on logits: exp2 (32x32 MFMA) and exp1 (128^2, 2 blocks/CU) run first,
//     authoritative 256^2 kernel writes out last. Faster 64^2-tile transposes.

#define SS 2048
#define EE 1024
#define NH 16
#define FF 4096
#define NV 32000
#define NL 8

typedef _Float16 f16;
typedef _Float16 f16x8 __attribute__((ext_vector_type(8)));
typedef _Float16 f16x4 __attribute__((ext_vector_type(4)));
typedef float f32x4 __attribute__((ext_vector_type(4)));
typedef float f32x16 __attribute__((ext_vector_type(16)));

#define CS 4096.0f          // 2^12 activation scale
#define INV_CS 0.000244140625f
#define SCORE_SCALE 7.450580596923828e-09f  // 1/(8*CS^2) = 2^-27

__device__ __forceinline__ void gload16(const void* g, void* lds) {
    __builtin_amdgcn_global_load_lds(
        (const __attribute__((address_space(1))) unsigned int*)g,
        (__attribute__((address_space(3))) unsigned int*)lds, 16, 0, 0);
}

#define BAR do { asm volatile("" ::: "memory"); __builtin_amdgcn_s_barrier(); } while (0)

// ---------------- embedding gather (fp32 -> fp16 * CS) ----------------
__global__ void k_embed(const int* __restrict__ ids, const float* __restrict__ emb,
                        f16* __restrict__ xh) {
    int s = blockIdx.x;
    int e = threadIdx.x * 4;
    const float4 v = *(const float4*)&emb[(size_t)ids[s] * EE + e];
    f16x4 h;
    h[0] = (f16)(v.x * CS); h[1] = (f16)(v.y * CS);
    h[2] = (f16)(v.z * CS); h[3] = (f16)(v.w * CS);
    *(f16x4*)&xh[(size_t)s * EE + e] = h;
}

// ---------------- 64x64 transpose tile: fp32 in -> fp16 out ----------------
__device__ __forceinline__ void tr64(const float* __restrict__ in, f16* __restrict__ out,
                                     int ldi, int ldo, int bx, int by) {
    __shared__ float tl[64][65];
    const int tx = threadIdx.x & 15, ty = threadIdx.x >> 4;
#pragma unroll
    for (int i = 0; i < 4; i++) {
        float4 v = *(const float4*)&in[(size_t)(by + ty * 4 + i) * ldi + bx + tx * 4];
        tl[ty * 4 + i][tx * 4 + 0] = v.x;
        tl[ty * 4 + i][tx * 4 + 1] = v.y;
        tl[ty * 4 + i][tx * 4 + 2] = v.z;
        tl[ty * 4 + i][tx * 4 + 3] = v.w;
    }
    __syncthreads();
#pragma unroll
    for (int i = 0; i < 4; i++) {
        f16x4 h;
#pragma unroll
        for (int j = 0; j < 4; j++) h[j] = (f16)tl[tx * 4 + j][ty * 4 + i];
        *(f16x4*)&out[(size_t)(bx + ty * 4 + i) * ldo + by + tx * 4] = h;
    }
}

// fused per-layer weight transposes + bias concat (grid 2817, 256 thr)
__global__ void k_trW(const float* __restrict__ Wq, const float* __restrict__ Wk,
                      const float* __restrict__ Wv, const float* __restrict__ W1,
                      const float* __restrict__ W2,
                      const float* __restrict__ bq, const float* __restrict__ bk,
                      const float* __restrict__ bv,
                      f16* __restrict__ wqkvt, f16* __restrict__ w1t,
                      f16* __restrict__ w2t, float* __restrict__ bqkv) {
    int b = blockIdx.x;
    if (b == 2816) {
        int i = threadIdx.x;
#pragma unroll
        for (int j = 0; j < 12; j++) {
            int idx = j * 256 + i;
            bqkv[idx] = idx < EE ? bq[idx] : (idx < 2 * EE ? bk[idx - EE] : bv[idx - 2 * EE]);
        }
        return;
    }
    if (b < 768) {          // Wq/Wk/Wv [1024][1024] -> wqkvt, 16x16 tiles each
        int s = b >> 8, t2 = b & 255;
        tr64(s == 0 ? Wq : (s == 1 ? Wk : Wv), wqkvt + (size_t)s * EE * EE,
             EE, EE, (t2 & 15) * 64, (t2 >> 4) * 64);
    } else if (b < 1792) {  // W1 [1024][4096] -> w1t [4096][1024]: 64x x 16y tiles
        int t2 = b - 768;
        tr64(W1, w1t, FF, EE, (t2 & 63) * 64, (t2 >> 6) * 64);
    } else {                // W2 [4096][1024] -> w2t [1024][4096]: 16x x 64y tiles
        int t2 = b - 1792;
        tr64(W2, w2t, EE, FF, (t2 & 15) * 64, (t2 >> 4) * 64);
    }
}

// Wout [1024][32000] -> woutt [32000][1024] (grid 8000, 256 thr)
__global__ void k_trOut(const float* __restrict__ in, f16* __restrict__ out) {
    int b = blockIdx.x;
    tr64(in, out, NV, EE, (b % 500) * 64, (b / 500) * 64);
}

// split-K=4 combiner: out = f16(p0+p1+p2+p3 + bias*CS)
__global__ void k_combine4(const float* __restrict__ part, const float* __restrict__ bias,
                           f16* __restrict__ out) {
    const size_t sz = (size_t)SS * EE;
    int i = (blockIdx.x * 256 + threadIdx.x) * 4;
    float4 a = *(const float4*)&part[i];
    float4 b = *(const float4*)&part[i + sz];
    float4 c = *(const float4*)&part[i + 2 * sz];
    float4 d = *(const float4*)&part[i + 3 * sz];
    float4 bb = *(const float4*)&bias[i & (EE - 1)];
    f16x4 h;
    h[0] = (f16)(a.x + b.x + c.x + d.x + bb.x * CS);
    h[1] = (f16)(a.y + b.y + c.y + d.y + bb.y * CS);
    h[2] = (f16)(a.z + b.z + c.z + d.z + bb.z * CS);
    h[3] = (f16)(a.w + b.w + c.w + d.w + bb.w * CS);
    *(f16x4*)&out[i] = h;
}

// ================= GEMM (R3 schedule): C[M,N] = A[M,K] * B[N,K]^T =================
// BK=64, LDS dbuf, both-sides XOR swizzle. Per K-tile: {bulk ds_read + setprio MFMA} x2ks,
// then BAR; STAGE(tt+2); vmcnt(LPT); BAR. (BM,BN): (256,256) 8w 2x4 MR=8; (256,128) 8w 4x2
// MR=4; (128,128) 4w 2x2 MR=4 -> 64KB LDS = 2 blocks/CU (exp1: cross-block overlap).
template<int BM, int BN, int TAG>
__global__ __launch_bounds__((BM == 128) ? 256 : 512, 2) void k_gemm(
    const f16* __restrict__ A, const f16* __restrict__ B,
    const float* __restrict__ bias, f16* __restrict__ Ch, float* __restrict__ Cf,
    f16* __restrict__ VtOut,
    int M, int N, int Kstride, int Ksub, int nm, int nn, int kch,
    float bscale, float oscale, int relu) {
    constexpr int WR = (BM == 256) ? ((BN == 256) ? 2 : 4) : 2;
    constexpr int WC = (BN == 256) ? 4 : 2;
    constexpr int NW = WR * WC;
    constexpr int THREADS = NW * 64;
    constexpr int MR = BM / WR / 16;
    constexpr int RPC = THREADS / 8;        // LDS rows covered per gload16 call
    constexpr int ACALLS = BM / RPC;
    constexpr int BCALLS = BN / RPC;
    constexpr int LPT = ACALLS + BCALLS;

    __shared__ f16 As[2][BM * 64];
    __shared__ f16 Bs[2][BN * 64];

    const int t = threadIdx.x;
    const int l = t & 63, w = t >> 6;
    const int lr = l & 15, lc = l >> 4;

    const int nwg = nm * nn * kch;
    const int q8 = nwg >> 3, r8 = nwg & 7;
    const int xcd = blockIdx.x & 7, lid = blockIdx.x >> 3;
    const int wgid = (xcd < r8 ? xcd * (q8 + 1) : r8 * (q8 + 1) + (xcd - r8) * q8) + lid;
    const int kc = wgid / (nm * nn);
    const int rem = wgid - kc * (nm * nn);
    const int m0 = (rem % nm) * BM, n0 = (rem / nm) * BN;

    const f16* Ab = A + (size_t)kc * Ksub;
    const f16* Bb = B + (size_t)kc * Ksub;
    float* Cfb = Cf ? Cf + (size_t)kc * M * N : nullptr;

    const int wr = w / WC, wc = w % WC;

    f32x4 acc[MR][4] = {};

    const int srow = t >> 3;
    const int scol = 8 * ((t & 7) ^ (srow & 7));
    const int NT = Ksub / 64;

#define STAGE(bb, tt_) { \
    const size_t kof = (size_t)(tt_) * 64 + scol; \
    _Pragma("unroll") \
    for (int c = 0; c < ACALLS; c++) \
        gload16(Ab + (size_t)(m0 + c * RPC + srow) * Kstride + kof, \
                (char*)As[bb] + c * (RPC * 128) + w * 1024); \
    _Pragma("unroll") \
    for (int c = 0; c < BCALLS; c++) \
        gload16(Bb + (size_t)(n0 + c * RPC + srow) * Kstride + kof, \
                (char*)Bs[bb] + c * (RPC * 128) + w * 1024); }

    STAGE(0, 0)
    STAGE(1, 1)
    asm volatile("s_waitcnt vmcnt(%0)" :: "n"(LPT) : "memory");
    BAR;

    int cur = 0;
    for (int tt = 0; tt < NT; ++tt) {
        const f16* pA = As[cur];
        const f16* pB = Bs[cur];
#pragma unroll
        for (int ks = 0; ks < 2; ks++) {
            f16x8 af[MR], bf[4];
#pragma unroll
            for (int m = 0; m < MR; m++) {
                const int row = wr * (MR * 16) + m * 16 + lr;
                af[m] = *(const f16x8*)&pA[row * 64 + 8 * ((ks * 4 + lc) ^ (row & 7))];
            }
#pragma unroll
            for (int n = 0; n < 4; n++) {
                const int row = wc * 64 + n * 16 + lr;
                bf[n] = *(const f16x8*)&pB[row * 64 + 8 * ((ks * 4 + lc) ^ (row & 7))];
            }
            __builtin_amdgcn_s_setprio(1);
#pragma unroll
            for (int m = 0; m < MR; m++)
#pragma unroll
                for (int n = 0; n < 4; n++)
                    acc[m][n] = __builtin_amdgcn_mfma_f32_16x16x32_f16(af[m], bf[n], acc[m][n], 0, 0, 0);
            __builtin_amdgcn_s_setprio(0);
        }
        BAR;                                // all waves done reading buf[cur]
        if (tt + 2 < NT) {
            STAGE(cur, tt + 2)
            asm volatile("s_waitcnt vmcnt(%0)" :: "n"(LPT) : "memory");  // tile tt+1 landed
        } else if (tt + 1 < NT) {
            asm volatile("s_waitcnt vmcnt(0)" ::: "memory");
        }
        BAR;
        cur ^= 1;
    }
#undef STAGE

    // epilogue: C/D layout col=lane&15, row=(lane>>4)*4+reg
#pragma unroll
    for (int m = 0; m < MR; m++)
#pragma unroll
        for (int n = 0; n < 4; n++) {
            const int row0 = m0 + wr * (MR * 16) + m * 16 + lc * 4;
            const int col = n0 + wc * 64 + n * 16 + lr;
            float v[4];
#pragma unroll
            for (int r = 0; r < 4; r++) {
                v[r] = acc[m][n][r];
                if (bias) v[r] += bias[col] * bscale;
                if (relu) v[r] = fmaxf(v[r], 0.0f);
            }
            if (VtOut && col >= 2 * EE) {
                f16x4 h4;
#pragma unroll
                for (int r = 0; r < 4; r++) h4[r] = (f16)v[r];
                *(f16x4*)&VtOut[(size_t)(col - 2 * EE) * SS + row0] = h4;
            } else if (Ch) {
#pragma unroll
                for (int r = 0; r < 4; r++)
                    Ch[(size_t)(row0 + r) * N + col] = (f16)v[r];
            } else {
#pragma unroll
                for (int r = 0; r < 4; r++)
                    Cfb[(size_t)(row0 + r) * N + col] = v[r] * oscale;
            }
        }
}

// ================= exp2: 256^2 GEMM with mfma_f32_32x32x16_f16 =================
// 8 waves 2x4, wave 128x64 = 4 m-frags x 2 n-frags of 32x32; R3 schedule.
// A/B frag: lane holds row(col)=l&31, k=(l>>5)*8..+8. C/D: col=l&31,
// row=(reg&3)+8*(reg>>2)+4*(l>>5)  [guide §3, m74/m101].
__global__ __launch_bounds__(512, 2) void k_gemm32(
    const f16* __restrict__ A, const f16* __restrict__ B, float* __restrict__ Cf,
    int N, int Kstride, int nm, int nn, float oscale) {
    __shared__ f16 As[2][256 * 64];
    __shared__ f16 Bs[2][256 * 64];
    const int t = threadIdx.x;
    const int l = t & 63, w = t >> 6;
    const int ln = l & 31, hi = l >> 5;

    const int nwg = nm * nn;
    const int q8 = nwg >> 3, r8 = nwg & 7;
    const int xcd = blockIdx.x & 7, lid = blockIdx.x >> 3;
    const int wgid = (xcd < r8 ? xcd * (q8 + 1) : r8 * (q8 + 1) + (xcd - r8) * q8) + lid;
    const int m0 = (wgid % nm) * 256, n0 = (wgid / nm) * 256;

    const int wr = w >> 2, wc = w & 3;
    f32x16 acc[4][2] = {};

    const int srow = t >> 3;
    const int scol = 8 * ((t & 7) ^ (srow & 7));
    const int NT = Kstride / 64;

#define STAGE32(bb, tt_) { \
    const size_t kof = (size_t)(tt_) * 64 + scol; \
    _Pragma("unroll") \
    for (int c = 0; c < 4; c++) { \
        gload16(A + (size_t)(m0 + c * 64 + srow) * Kstride + kof, \
                (char*)As[bb] + c * 8192 + w * 1024); \
        gload16(B + (size_t)(n0 + c * 64 + srow) * Kstride + kof, \
                (char*)Bs[bb] + c * 8192 + w * 1024); } }

    STAGE32(0, 0)
    STAGE32(1, 1)
    asm volatile("s_waitcnt vmcnt(8)" ::: "memory");
    BAR;

    int cur = 0;
    for (int tt = 0; tt < NT; ++tt) {
        const f16* pA = As[cur];
        const f16* pB = Bs[cur];
#pragma unroll
        for (int ks = 0; ks < 4; ks++) {     // K=16 per mfma, 4 steps over BK=64
            f16x8 af[4], bf[2];
#pragma unroll
            for (int m = 0; m < 4; m++) {
                const int row = wr * 128 + m * 32 + ln;
                af[m] = *(const f16x8*)&pA[row * 64 + 8 * ((ks * 2 + hi) ^ (row & 7))];
            }
#pragma unroll
            for (int n = 0; n < 2; n++) {
                const int row = wc * 64 + n * 32 + ln;
                bf[n] = *(const f16x8*)&pB[row * 64 + 8 * ((ks * 2 + hi) ^ (row & 7))];
            }
            __builtin_amdgcn_s_setprio(1);
#pragma unroll
            for (int m = 0; m < 4; m++)
#pragma unroll
                for (int n = 0; n < 2; n++)
                    acc[m][n] = __builtin_amdgcn_mfma_f32_32x32x16_f16(af[m], bf[n], acc[m][n], 0, 0, 0);
            __builtin_amdgcn_s_setprio(0);
        }
        BAR;
        if (tt + 2 < NT) {
            STAGE32(cur, tt + 2)
            asm volatile("s_waitcnt vmcnt(8)" ::: "memory");
        } else if (tt + 1 < NT) {
            asm volatile("s_waitcnt vmcnt(0)" ::: "memory");
        }
        BAR;
        cur ^= 1;
    }
#undef STAGE32

#pragma unroll
    for (int m = 0; m < 4; m++)
#pragma unroll
        for (int n = 0; n < 2; n++)
#pragma unroll
            for (int r = 0; r < 16; r++) {
                const int row = m0 + wr * 128 + m * 32 + (r & 3) + 8 * (r >> 2) + 4 * hi;
                const int col = n0 + wc * 64 + n * 32 + ln;
                Cf[(size_t)row * N + col] = acc[m][n][r] * oscale;
            }
}

// ---------------- flash attention (counted-vmcnt pipeline) ----------------
__global__ __launch_bounds__(256) void k_flash(
    const f16* __restrict__ qkv, const f16* __restrict__ vt, f16* __restrict__ attn) {
    __shared__ f16 Ks[2][4096];
    __shared__ f16 Vs[2][4096];
    __shared__ f16 Ps[4096];
    const int h = blockIdx.x;
    const int qb = blockIdx.y;
    const int t = threadIdx.x, l = t & 63, w = t >> 6;
    const int lr = l & 15, lc = l >> 4;
    const int q0 = qb * 64;
    const int qrow = q0 + w * 16 + lr;

    f16x8 qf0 = *(const f16x8*)&qkv[(size_t)qrow * 3072 + h * 64 + lc * 8];
    f16x8 qf1 = *(const f16x8*)&qkv[(size_t)qrow * 3072 + h * 64 + 32 + lc * 8];

    f32x4 o[4] = {};
    float mrun[4], lrun[4];
#pragma unroll
    for (int r = 0; r < 4; r++) { mrun[r] = -__builtin_inff(); lrun[r] = 0.0f; }

    const int krow = t >> 3;
    const int kscol = 8 * ((t & 7) ^ (krow & 7));
    const f16* gK = qkv + EE + h * 64;
    const f16* gV = vt + (size_t)(h * 64) * SS;
    f16* Pw = &Ps[w * 16 * 64];
    const int psw = (lr & 7) << 4;

#define FSTAGE(bb, kt_) { \
    char* dK = (char*)Ks[bb] + w * 1024; \
    char* dV = (char*)Vs[bb] + w * 1024; \
    gload16(gK + (size_t)((kt_) * 64 + krow) * 3072 + kscol, dK); \
    gload16(gK + (size_t)((kt_) * 64 + krow + 32) * 3072 + kscol, dK + 4096); \
    gload16(gV + (size_t)krow * SS + (kt_) * 64 + kscol, dV); \
    gload16(gV + (size_t)(krow + 32) * SS + (kt_) * 64 + kscol, dV + 4096); }

    const int nkt = qb + 1;
    FSTAGE(0, 0)
    FSTAGE(1, 1)
    asm volatile("s_waitcnt vmcnt(4)" ::: "memory");
    __builtin_amdgcn_s_barrier();

    int cur = 0;
    for (int kt = 0; kt < nkt; kt++) {
        f32x4 sc[4];
        __builtin_amdgcn_s_setprio(1);
#pragma unroll
        for (int kj = 0; kj < 4; kj++) {
            const int krw = kj * 16 + lr;
            const int sw = krw & 7;
            f16x8 kb0 = *(const f16x8*)&Ks[cur][krw * 64 + 8 * (lc ^ sw)];
            f16x8 kb1 = *(const f16x8*)&Ks[cur][krw * 64 + 8 * ((lc + 4) ^ sw)];
            f32x4 z = {};
            z = __builtin_amdgcn_mfma_f32_16x16x32_f16(qf0, kb0, z, 0, 0, 0);
            z = __builtin_amdgcn_mfma_f32_16x16x32_f16(qf1, kb1, z, 0, 0, 0);
            sc[kj] = z;
        }
        __builtin_amdgcn_s_setprio(0);

        const bool diag = (kt == qb);
#pragma unroll
        for (int kj = 0; kj < 4; kj++)
#pragma unroll
            for (int r = 0; r < 4; r++) {
                float v = sc[kj][r] * SCORE_SCALE;
                if (diag) {
                    int qq = w * 16 + lc * 4 + r;
                    int kk = kj * 16 + lr;
                    if (kk > qq) v = -__builtin_inff();
                }
                sc[kj][r] = v;
            }

#pragma unroll
        for (int r = 0; r < 4; r++) {
            float mt = fmaxf(fmaxf(sc[0][r], sc[1][r]), fmaxf(sc[2][r], sc[3][r]));
            mt = fmaxf(mt, __shfl_xor(mt, 1));
            mt = fmaxf(mt, __shfl_xor(mt, 2));
            mt = fmaxf(mt, __shfl_xor(mt, 4));
            mt = fmaxf(mt, __shfl_xor(mt, 8));
            float mnew = fmaxf(mrun[r], mt);
            float alpha = __expf(mrun[r] - mnew);
            float psum = 0.0f;
#pragma unroll
            for (int kj = 0; kj < 4; kj++) {
                float p = __expf(sc[kj][r] - mnew);
                sc[kj][r] = p;
                psum += p;
            }
            psum += __shfl_xor(psum, 1);
            psum += __shfl_xor(psum, 2);
            psum += __shfl_xor(psum, 4);
            psum += __shfl_xor(psum, 8);
            lrun[r] = lrun[r] * alpha + psum;
            mrun[r] = mnew;
#pragma unroll
            for (int dj = 0; dj < 4; dj++) o[dj][r] *= alpha;
        }

#pragma unroll
        for (int kj = 0; kj < 4; kj++)
#pragma unroll
            for (int r = 0; r < 4; r++) {
                int prow = lc * 4 + r;
                int pb = prow * 128 + ((kj * 16 + lr) * 2 ^ ((prow & 7) << 4));
                *(f16*)((char*)Pw + pb) = (f16)sc[kj][r];
            }

        __builtin_amdgcn_s_setprio(1);
#pragma unroll
        for (int s2 = 0; s2 < 2; s2++) {
            f16x8 pa = *(const f16x8*)((const char*)Pw + lr * 128 + (((lc + 4 * s2) * 16) ^ psw));
#pragma unroll
            for (int dj = 0; dj < 4; dj++) {
                const int vrow = dj * 16 + lr;
                f16x8 vb = *(const f16x8*)&Vs[cur][vrow * 64 + 8 * ((lc + 4 * s2) ^ (vrow & 7))];
                o[dj] = __builtin_amdgcn_mfma_f32_16x16x32_f16(pa, vb, o[dj], 0, 0, 0);
            }
        }
        __builtin_amdgcn_s_setprio(0);

        asm volatile("" ::: "memory");
        __builtin_amdgcn_s_barrier();
        if (kt + 2 < nkt) {
            FSTAGE(cur, kt + 2)
            asm volatile("s_waitcnt vmcnt(4)" ::: "memory");
        } else if (kt + 1 < nkt) {
            asm volatile("s_waitcnt vmcnt(0)" ::: "memory");
        }
        __builtin_amdgcn_s_barrier();
        cur ^= 1;
    }
#undef FSTAGE

#pragma unroll
    for (int dj = 0; dj < 4; dj++)
#pragma unroll
        for (int r = 0; r < 4; r++) {
            float v = o[dj][r] / lrun[r];
            attn[(size_t)(q0 + w * 16 + lc * 4 + r) * EE + h * 64 + dj * 16 + lr] = (f16)v;
        }
}

// ---------------- host launch ----------------
extern "C" void kernel_launch(void* const* d_in, const int* in_sizes, int n_in,
                              void* d_out, int out_size, void* d_ws, size_t ws_size,
                              hipStream_t stream) {
    const int*   ids  = (const int*)d_in[0];
    const float* emb  = (const float*)d_in[2];
    const float* Wq   = (const float*)d_in[3];
    const float* bq   = (const float*)d_in[4];
    const float* Wk   = (const float*)d_in[5];
    const float* bk   = (const float*)d_in[6];
    const float* Wv   = (const float*)d_in[7];
    const float* bv   = (const float*)d_in[8];
    const float* W1   = (const float*)d_in[9];
    const float* b1   = (const float*)d_in[10];
    const float* W2   = (const float*)d_in[11];
    const float* b2   = (const float*)d_in[12];
    const float* Wout = (const float*)d_in[13];
    float* out = (float*)d_out;

    char* p = (char*)d_ws;
    f16* xh    = (f16*)p; p += (size_t)SS * EE * 2;        // 4 MB
    f16* qkvh  = (f16*)p; p += (size_t)SS * 3 * EE * 2;    // 12 MB
    f16* vt    = (f16*)p; p += (size_t)EE * SS * 2;        // 4 MB
    f16* attn  = (f16*)p; p += (size_t)SS * EE * 2;        // 4 MB
    f16* h1    = (f16*)p; p += (size_t)SS * FF * 2;        // 16 MB
    f16* wqkvt = (f16*)p; p += (size_t)3 * EE * EE * 2;    // 6 MB
    f16* w1t   = (f16*)p; p += (size_t)FF * EE * 2;        // 8 MB
    f16* w2t   = (f16*)p; p += (size_t)EE * FF * 2;        // 8 MB
    f16* woutt = (f16*)p; p += (size_t)NV * EE * 2;        // 64 MB
    float* part = (float*)p; p += (size_t)4 * SS * EE * 4; // 32 MB
    float* bqkv = (float*)p; p += 3 * EE * 4;

    k_embed<<<SS, 256, 0, stream>>>(ids, emb, xh);

    for (int l = 0; l < NL; l++) {
        k_trW<<<2817, 256, 0, stream>>>(
            Wq + (size_t)l * EE * EE, Wk + (size_t)l * EE * EE, Wv + (size_t)l * EE * EE,
            W1 + (size_t)l * EE * FF, W2 + (size_t)l * FF * EE,
            bq + l * EE, bk + l * EE, bv + l * EE,
            wqkvt, w1t, w2t, bqkv);

        // QKV: [2048,1024] x [3072,1024]^T -> qkvh (Q,K) + vt (V^T). grid 8*24=192
        k_gemm<256, 128, 1><<<8 * 24, 512, 0, stream>>>(
            xh, wqkvt, bqkv, qkvh, nullptr, vt, SS, 3 * EE, EE, EE, 8, 24, 1, CS, 1.0f, 0);

        k_flash<<<dim3(NH, SS / 64), 256, 0, stream>>>(qkvh, vt, attn);

        // FFN1 + relu: grid 8*32=256
        k_gemm<256, 128, 2><<<8 * 32, 512, 0, stream>>>(
            attn, w1t, b1 + (size_t)l * FF, h1, nullptr, nullptr, SS, FF, EE, EE, 8, 32, 1, CS, 1.0f, 1);

        // FFN2 split-K=4: grid 8*8*4=256
        k_gemm<256, 128, 3><<<8 * 8 * 4, 512, 0, stream>>>(
            h1, w2t, nullptr, nullptr, part, nullptr, SS, EE, FF, FF / 4, 8, 8, 4, 0.0f, 1.0f, 0);
        k_combine4<<<SS * EE / 1024, 256, 0, stream>>>(part, b2 + (size_t)l * EE, xh);
    }

    // logits: [2048,1024] x [32000,1024]^T -> fp32 out, unscale 1/CS
    k_trOut<<<8000, 256, 0, stream>>>(Wout, woutt);

    // exp2 (A/B probe): 32x32 MFMA variant. grid 8*125=1000
    k_gemm32<<<8 * 125, 512, 0, stream>>>(xh, woutt, out, NV, EE, 8, 125, INV_CS);

    // exp1 (A/B probe): 128^2 tile, 2 blocks/CU. grid 16*250=4000
    k_gemm<128, 128, 8><<<16 * 250, 256, 0, stream>>>(
        xh, woutt, nullptr, nullptr, out, nullptr, SS, NV, EE, EE, 16, 250, 1, 0.0f, INV_CS, 0);

    // authoritative logits (writes out LAST): 256^2 R3 schedule. grid 8*125=1000
    k_gemm<256, 256, 9><<<8 * 125, 512, 0, stream>>>(
        xh, woutt, nullptr, nullptr, out, nullptr, SS, NV, EE, EE, 8, 125, 1, 0.0f, INV_CS, 0);
}

// Round 7
// 1540.218 us; speedup vs baseline: 1.2679x; 1.2679x over previous
//
#include <hip/hip_runtime.h>
#include <hip/hip_fp16.h>

// StackedAttentionModel: 8-layer transformer fwd, S=2048 E=1024 H=16 D=64 F=4096 V=32000.
// fp16 MFMA (fp32 accum), global activation scale CS=2^12 folded out exactly.
// R7: probes removed; logits on 32x32x16 MFMA (k_gemm32, ~20-40% faster per R6 A/B arithmetic);
//     flash heavy-first dispatch (qb reversed) to kill the causal straggler tail;
//     layer GEMMs stay on validated 16x16 R3 schedule.

#define SS 2048
#define EE 1024
#define NH 16
#define FF 4096
#define NV 32000
#define NL 8

typedef _Float16 f16;
typedef _Float16 f16x8 __attribute__((ext_vector_type(8)));
typedef _Float16 f16x4 __attribute__((ext_vector_type(4)));
typedef float f32x4 __attribute__((ext_vector_type(4)));
typedef float f32x16 __attribute__((ext_vector_type(16)));

#define CS 4096.0f          // 2^12 activation scale
#define INV_CS 0.000244140625f
#define SCORE_SCALE 7.450580596923828e-09f  // 1/(8*CS^2) = 2^-27

__device__ __forceinline__ void gload16(const void* g, void* lds) {
    __builtin_amdgcn_global_load_lds(
        (const __attribute__((address_space(1))) unsigned int*)g,
        (__attribute__((address_space(3))) unsigned int*)lds, 16, 0, 0);
}

#define BAR do { asm volatile("" ::: "memory"); __builtin_amdgcn_s_barrier(); } while (0)

// ---------------- embedding gather (fp32 -> fp16 * CS) ----------------
__global__ void k_embed(const int* __restrict__ ids, const float* __restrict__ emb,
                        f16* __restrict__ xh) {
    int s = blockIdx.x;
    int e = threadIdx.x * 4;
    const float4 v = *(const float4*)&emb[(size_t)ids[s] * EE + e];
    f16x4 h;
    h[0] = (f16)(v.x * CS); h[1] = (f16)(v.y * CS);
    h[2] = (f16)(v.z * CS); h[3] = (f16)(v.w * CS);
    *(f16x4*)&xh[(size_t)s * EE + e] = h;
}

// ---------------- 64x64 transpose tile: fp32 in -> fp16 out ----------------
__device__ __forceinline__ void tr64(const float* __restrict__ in, f16* __restrict__ out,
                                     int ldi, int ldo, int bx, int by) {
    __shared__ float tl[64][65];
    const int tx = threadIdx.x & 15, ty = threadIdx.x >> 4;
#pragma unroll
    for (int i = 0; i < 4; i++) {
        float4 v = *(const float4*)&in[(size_t)(by + ty * 4 + i) * ldi + bx + tx * 4];
        tl[ty * 4 + i][tx * 4 + 0] = v.x;
        tl[ty * 4 + i][tx * 4 + 1] = v.y;
        tl[ty * 4 + i][tx * 4 + 2] = v.z;
        tl[ty * 4 + i][tx * 4 + 3] = v.w;
    }
    __syncthreads();
#pragma unroll
    for (int i = 0; i < 4; i++) {
        f16x4 h;
#pragma unroll
        for (int j = 0; j < 4; j++) h[j] = (f16)tl[tx * 4 + j][ty * 4 + i];
        *(f16x4*)&out[(size_t)(bx + ty * 4 + i) * ldo + by + tx * 4] = h;
    }
}

// fused per-layer weight transposes + bias concat (grid 2817, 256 thr)
__global__ void k_trW(const float* __restrict__ Wq, const float* __restrict__ Wk,
                      const float* __restrict__ Wv, const float* __restrict__ W1,
                      const float* __restrict__ W2,
                      const float* __restrict__ bq, const float* __restrict__ bk,
                      const float* __restrict__ bv,
                      f16* __restrict__ wqkvt, f16* __restrict__ w1t,
                      f16* __restrict__ w2t, float* __restrict__ bqkv) {
    int b = blockIdx.x;
    if (b == 2816) {
        int i = threadIdx.x;
#pragma unroll
        for (int j = 0; j < 12; j++) {
            int idx = j * 256 + i;
            bqkv[idx] = idx < EE ? bq[idx] : (idx < 2 * EE ? bk[idx - EE] : bv[idx - 2 * EE]);
        }
        return;
    }
    if (b < 768) {          // Wq/Wk/Wv [1024][1024] -> wqkvt, 16x16 tiles each
        int s = b >> 8, t2 = b & 255;
        tr64(s == 0 ? Wq : (s == 1 ? Wk : Wv), wqkvt + (size_t)s * EE * EE,
             EE, EE, (t2 & 15) * 64, (t2 >> 4) * 64);
    } else if (b < 1792) {  // W1 [1024][4096] -> w1t [4096][1024]
        int t2 = b - 768;
        tr64(W1, w1t, FF, EE, (t2 & 63) * 64, (t2 >> 6) * 64);
    } else {                // W2 [4096][1024] -> w2t [1024][4096]
        int t2 = b - 1792;
        tr64(W2, w2t, EE, FF, (t2 & 15) * 64, (t2 >> 4) * 64);
    }
}

// Wout [1024][32000] -> woutt [32000][1024] (grid 8000, 256 thr)
__global__ void k_trOut(const float* __restrict__ in, f16* __restrict__ out) {
    int b = blockIdx.x;
    tr64(in, out, NV, EE, (b % 500) * 64, (b / 500) * 64);
}

// split-K=4 combiner: out = f16(p0+p1+p2+p3 + bias*CS)
__global__ void k_combine4(const float* __restrict__ part, const float* __restrict__ bias,
                           f16* __restrict__ out) {
    const size_t sz = (size_t)SS * EE;
    int i = (blockIdx.x * 256 + threadIdx.x) * 4;
    float4 a = *(const float4*)&part[i];
    float4 b = *(const float4*)&part[i + sz];
    float4 c = *(const float4*)&part[i + 2 * sz];
    float4 d = *(const float4*)&part[i + 3 * sz];
    float4 bb = *(const float4*)&bias[i & (EE - 1)];
    f16x4 h;
    h[0] = (f16)(a.x + b.x + c.x + d.x + bb.x * CS);
    h[1] = (f16)(a.y + b.y + c.y + d.y + bb.y * CS);
    h[2] = (f16)(a.z + b.z + c.z + d.z + bb.z * CS);
    h[3] = (f16)(a.w + b.w + c.w + d.w + bb.w * CS);
    *(f16x4*)&out[i] = h;
}

// ================= GEMM (R3 schedule): C[M,N] = A[M,K] * B[N,K]^T =================
// BK=64, LDS dbuf, both-sides XOR swizzle. Per K-tile: {bulk ds_read + setprio MFMA} x2ks,
// then BAR; STAGE(tt+2); vmcnt(LPT); BAR.
template<int BM, int BN, int TAG>
__global__ __launch_bounds__((BM == 128) ? 256 : 512, 2) void k_gemm(
    const f16* __restrict__ A, const f16* __restrict__ B,
    const float* __restrict__ bias, f16* __restrict__ Ch, float* __restrict__ Cf,
    f16* __restrict__ VtOut,
    int M, int N, int Kstride, int Ksub, int nm, int nn, int kch,
    float bscale, float oscale, int relu) {
    constexpr int WR = (BM == 256) ? ((BN == 256) ? 2 : 4) : 2;
    constexpr int WC = (BN == 256) ? 4 : 2;
    constexpr int NW = WR * WC;
    constexpr int THREADS = NW * 64;
    constexpr int MR = BM / WR / 16;
    constexpr int RPC = THREADS / 8;
    constexpr int ACALLS = BM / RPC;
    constexpr int BCALLS = BN / RPC;
    constexpr int LPT = ACALLS + BCALLS;

    __shared__ f16 As[2][BM * 64];
    __shared__ f16 Bs[2][BN * 64];

    const int t = threadIdx.x;
    const int l = t & 63, w = t >> 6;
    const int lr = l & 15, lc = l >> 4;

    const int nwg = nm * nn * kch;
    const int q8 = nwg >> 3, r8 = nwg & 7;
    const int xcd = blockIdx.x & 7, lid = blockIdx.x >> 3;
    const int wgid = (xcd < r8 ? xcd * (q8 + 1) : r8 * (q8 + 1) + (xcd - r8) * q8) + lid;
    const int kc = wgid / (nm * nn);
    const int rem = wgid - kc * (nm * nn);
    const int m0 = (rem % nm) * BM, n0 = (rem / nm) * BN;

    const f16* Ab = A + (size_t)kc * Ksub;
    const f16* Bb = B + (size_t)kc * Ksub;
    float* Cfb = Cf ? Cf + (size_t)kc * M * N : nullptr;

    const int wr = w / WC, wc = w % WC;

    f32x4 acc[MR][4] = {};

    const int srow = t >> 3;
    const int scol = 8 * ((t & 7) ^ (srow & 7));
    const int NT = Ksub / 64;

#define STAGE(bb, tt_) { \
    const size_t kof = (size_t)(tt_) * 64 + scol; \
    _Pragma("unroll") \
    for (int c = 0; c < ACALLS; c++) \
        gload16(Ab + (size_t)(m0 + c * RPC + srow) * Kstride + kof, \
                (char*)As[bb] + c * (RPC * 128) + w * 1024); \
    _Pragma("unroll") \
    for (int c = 0; c < BCALLS; c++) \
        gload16(Bb + (size_t)(n0 + c * RPC + srow) * Kstride + kof, \
                (char*)Bs[bb] + c * (RPC * 128) + w * 1024); }

    STAGE(0, 0)
    STAGE(1, 1)
    asm volatile("s_waitcnt vmcnt(%0)" :: "n"(LPT) : "memory");
    BAR;

    int cur = 0;
    for (int tt = 0; tt < NT; ++tt) {
        const f16* pA = As[cur];
        const f16* pB = Bs[cur];
#pragma unroll
        for (int ks = 0; ks < 2; ks++) {
            f16x8 af[MR], bf[4];
#pragma unroll
            for (int m = 0; m < MR; m++) {
                const int row = wr * (MR * 16) + m * 16 + lr;
                af[m] = *(const f16x8*)&pA[row * 64 + 8 * ((ks * 4 + lc) ^ (row & 7))];
            }
#pragma unroll
            for (int n = 0; n < 4; n++) {
                const int row = wc * 64 + n * 16 + lr;
                bf[n] = *(const f16x8*)&pB[row * 64 + 8 * ((ks * 4 + lc) ^ (row & 7))];
            }
            __builtin_amdgcn_s_setprio(1);
#pragma unroll
            for (int m = 0; m < MR; m++)
#pragma unroll
                for (int n = 0; n < 4; n++)
                    acc[m][n] = __builtin_amdgcn_mfma_f32_16x16x32_f16(af[m], bf[n], acc[m][n], 0, 0, 0);
            __builtin_amdgcn_s_setprio(0);
        }
        BAR;
        if (tt + 2 < NT) {
            STAGE(cur, tt + 2)
            asm volatile("s_waitcnt vmcnt(%0)" :: "n"(LPT) : "memory");
        } else if (tt + 1 < NT) {
            asm volatile("s_waitcnt vmcnt(0)" ::: "memory");
        }
        BAR;
        cur ^= 1;
    }
#undef STAGE

    // epilogue: C/D layout col=lane&15, row=(lane>>4)*4+reg
#pragma unroll
    for (int m = 0; m < MR; m++)
#pragma unroll
        for (int n = 0; n < 4; n++) {
            const int row0 = m0 + wr * (MR * 16) + m * 16 + lc * 4;
            const int col = n0 + wc * 64 + n * 16 + lr;
            float v[4];
#pragma unroll
            for (int r = 0; r < 4; r++) {
                v[r] = acc[m][n][r];
                if (bias) v[r] += bias[col] * bscale;
                if (relu) v[r] = fmaxf(v[r], 0.0f);
            }
            if (VtOut && col >= 2 * EE) {
                f16x4 h4;
#pragma unroll
                for (int r = 0; r < 4; r++) h4[r] = (f16)v[r];
                *(f16x4*)&VtOut[(size_t)(col - 2 * EE) * SS + row0] = h4;
            } else if (Ch) {
#pragma unroll
                for (int r = 0; r < 4; r++)
                    Ch[(size_t)(row0 + r) * N + col] = (f16)v[r];
            } else {
#pragma unroll
                for (int r = 0; r < 4; r++)
                    Cfb[(size_t)(row0 + r) * N + col] = v[r] * oscale;
            }
        }
}

// ================= logits: 256^2 GEMM with mfma_f32_32x32x16_f16 =================
// 8 waves 2x4, wave 128x64 = 4 m-frags x 2 n-frags of 32x32; R3 schedule.
// A/B frag: lane l -> row(col)=l&31, k=(l>>5)*8+j. C/D: col=l&31,
// row=(reg&3)+8*(reg>>2)+4*(l>>5)  [guide §3, m74/m101].
__global__ __launch_bounds__(512, 2) void k_gemm32(
    const f16* __restrict__ A, const f16* __restrict__ B, float* __restrict__ Cf,
    int N, int Kstride, int nm, int nn, float oscale) {
    __shared__ f16 As[2][256 * 64];
    __shared__ f16 Bs[2][256 * 64];
    const int t = threadIdx.x;
    const int l = t & 63, w = t >> 6;
    const int ln = l & 31, hi = l >> 5;

    const int nwg = nm * nn;
    const int q8 = nwg >> 3, r8 = nwg & 7;
    const int xcd = blockIdx.x & 7, lid = blockIdx.x >> 3;
    const int wgid = (xcd < r8 ? xcd * (q8 + 1) : r8 * (q8 + 1) + (xcd - r8) * q8) + lid;
    const int m0 = (wgid % nm) * 256, n0 = (wgid / nm) * 256;

    const int wr = w >> 2, wc = w & 3;
    f32x16 acc[4][2] = {};

    const int srow = t >> 3;
    const int scol = 8 * ((t & 7) ^ (srow & 7));
    const int NT = Kstride / 64;

#define STAGE32(bb, tt_) { \
    const size_t kof = (size_t)(tt_) * 64 + scol; \
    _Pragma("unroll") \
    for (int c = 0; c < 4; c++) { \
        gload16(A + (size_t)(m0 + c * 64 + srow) * Kstride + kof, \
                (char*)As[bb] + c * 8192 + w * 1024); \
        gload16(B + (size_t)(n0 + c * 64 + srow) * Kstride + kof, \
                (char*)Bs[bb] + c * 8192 + w * 1024); } }

    STAGE32(0, 0)
    STAGE32(1, 1)
    asm volatile("s_waitcnt vmcnt(8)" ::: "memory");
    BAR;

    int cur = 0;
    for (int tt = 0; tt < NT; ++tt) {
        const f16* pA = As[cur];
        const f16* pB = Bs[cur];
#pragma unroll
        for (int ks = 0; ks < 4; ks++) {     // K=16 per mfma, 4 steps over BK=64
            f16x8 af[4], bf[2];
#pragma unroll
            for (int m = 0; m < 4; m++) {
                const int row = wr * 128 + m * 32 + ln;
                af[m] = *(const f16x8*)&pA[row * 64 + 8 * ((ks * 2 + hi) ^ (row & 7))];
            }
#pragma unroll
            for (int n = 0; n < 2; n++) {
                const int row = wc * 64 + n * 32 + ln;
                bf[n] = *(const f16x8*)&pB[row * 64 + 8 * ((ks * 2 + hi) ^ (row & 7))];
            }
            __builtin_amdgcn_s_setprio(1);
#pragma unroll
            for (int m = 0; m < 4; m++)
#pragma unroll
                for (int n = 0; n < 2; n++)
                    acc[m][n] = __builtin_amdgcn_mfma_f32_32x32x16_f16(af[m], bf[n], acc[m][n], 0, 0, 0);
            __builtin_amdgcn_s_setprio(0);
        }
        BAR;
        if (tt + 2 < NT) {
            STAGE32(cur, tt + 2)
            asm volatile("s_waitcnt vmcnt(8)" ::: "memory");
        } else if (tt + 1 < NT) {
            asm volatile("s_waitcnt vmcnt(0)" ::: "memory");
        }
        BAR;
        cur ^= 1;
    }
#undef STAGE32

#pragma unroll
    for (int m = 0; m < 4; m++)
#pragma unroll
        for (int n = 0; n < 2; n++)
#pragma unroll
            for (int r = 0; r < 16; r++) {
                const int row = m0 + wr * 128 + m * 32 + (r & 3) + 8 * (r >> 2) + 4 * hi;
                const int col = n0 + wc * 64 + n * 32 + ln;
                Cf[(size_t)row * N + col] = acc[m][n][r] * oscale;
            }
}

// ---------------- flash attention (counted-vmcnt pipeline, heavy-first) ----------------
__global__ __launch_bounds__(256) void k_flash(
    const f16* __restrict__ qkv, const f16* __restrict__ vt, f16* __restrict__ attn) {
    __shared__ f16 Ks[2][4096];
    __shared__ f16 Vs[2][4096];
    __shared__ f16 Ps[4096];
    const int h = blockIdx.x;
    const int qb = (SS / 64 - 1) - blockIdx.y;   // heavy-first: qb=31 dispatches first
    const int t = threadIdx.x, l = t & 63, w = t >> 6;
    const int lr = l & 15, lc = l >> 4;
    const int q0 = qb * 64;
    const int qrow = q0 + w * 16 + lr;

    f16x8 qf0 = *(const f16x8*)&qkv[(size_t)qrow * 3072 + h * 64 + lc * 8];
    f16x8 qf1 = *(const f16x8*)&qkv[(size_t)qrow * 3072 + h * 64 + 32 + lc * 8];

    f32x4 o[4] = {};
    float mrun[4], lrun[4];
#pragma unroll
    for (int r = 0; r < 4; r++) { mrun[r] = -__builtin_inff(); lrun[r] = 0.0f; }

    const int krow = t >> 3;
    const int kscol = 8 * ((t & 7) ^ (krow & 7));
    const f16* gK = qkv + EE + h * 64;
    const f16* gV = vt + (size_t)(h * 64) * SS;
    f16* Pw = &Ps[w * 16 * 64];
    const int psw = (lr & 7) << 4;

#define FSTAGE(bb, kt_) { \
    char* dK = (char*)Ks[bb] + w * 1024; \
    char* dV = (char*)Vs[bb] + w * 1024; \
    gload16(gK + (size_t)((kt_) * 64 + krow) * 3072 + kscol, dK); \
    gload16(gK + (size_t)((kt_) * 64 + krow + 32) * 3072 + kscol, dK + 4096); \
    gload16(gV + (size_t)krow * SS + (kt_) * 64 + kscol, dV); \
    gload16(gV + (size_t)(krow + 32) * SS + (kt_) * 64 + kscol, dV + 4096); }

    const int nkt = qb + 1;
    FSTAGE(0, 0)
    FSTAGE(1, 1)
    asm volatile("s_waitcnt vmcnt(4)" ::: "memory");
    __builtin_amdgcn_s_barrier();

    int cur = 0;
    for (int kt = 0; kt < nkt; kt++) {
        f32x4 sc[4];
        __builtin_amdgcn_s_setprio(1);
#pragma unroll
        for (int kj = 0; kj < 4; kj++) {
            const int krw = kj * 16 + lr;
            const int sw = krw & 7;
            f16x8 kb0 = *(const f16x8*)&Ks[cur][krw * 64 + 8 * (lc ^ sw)];
            f16x8 kb1 = *(const f16x8*)&Ks[cur][krw * 64 + 8 * ((lc + 4) ^ sw)];
            f32x4 z = {};
            z = __builtin_amdgcn_mfma_f32_16x16x32_f16(qf0, kb0, z, 0, 0, 0);
            z = __builtin_amdgcn_mfma_f32_16x16x32_f16(qf1, kb1, z, 0, 0, 0);
            sc[kj] = z;
        }
        __builtin_amdgcn_s_setprio(0);

        const bool diag = (kt == qb);
#pragma unroll
        for (int kj = 0; kj < 4; kj++)
#pragma unroll
            for (int r = 0; r < 4; r++) {
                float v = sc[kj][r] * SCORE_SCALE;
                if (diag) {
                    int qq = w * 16 + lc * 4 + r;
                    int kk = kj * 16 + lr;
                    if (kk > qq) v = -__builtin_inff();
                }
                sc[kj][r] = v;
            }

#pragma unroll
        for (int r = 0; r < 4; r++) {
            float mt = fmaxf(fmaxf(sc[0][r], sc[1][r]), fmaxf(sc[2][r], sc[3][r]));
            mt = fmaxf(mt, __shfl_xor(mt, 1));
            mt = fmaxf(mt, __shfl_xor(mt, 2));
            mt = fmaxf(mt, __shfl_xor(mt, 4));
            mt = fmaxf(mt, __shfl_xor(mt, 8));
            float mnew = fmaxf(mrun[r], mt);
            float alpha = __expf(mrun[r] - mnew);
            float psum = 0.0f;
#pragma unroll
            for (int kj = 0; kj < 4; kj++) {
                float p = __expf(sc[kj][r] - mnew);
                sc[kj][r] = p;
                psum += p;
            }
            psum += __shfl_xor(psum, 1);
            psum += __shfl_xor(psum, 2);
            psum += __shfl_xor(psum, 4);
            psum += __shfl_xor(psum, 8);
            lrun[r] = lrun[r] * alpha + psum;
            mrun[r] = mnew;
#pragma unroll
            for (int dj = 0; dj < 4; dj++) o[dj][r] *= alpha;
        }

#pragma unroll
        for (int kj = 0; kj < 4; kj++)
#pragma unroll
            for (int r = 0; r < 4; r++) {
                int prow = lc * 4 + r;
                int pb = prow * 128 + ((kj * 16 + lr) * 2 ^ ((prow & 7) << 4));
                *(f16*)((char*)Pw + pb) = (f16)sc[kj][r];
            }

        __builtin_amdgcn_s_setprio(1);
#pragma unroll
        for (int s2 = 0; s2 < 2; s2++) {
            f16x8 pa = *(const f16x8*)((const char*)Pw + lr * 128 + (((lc + 4 * s2) * 16) ^ psw));
#pragma unroll
            for (int dj = 0; dj < 4; dj++) {
                const int vrow = dj * 16 + lr;
                f16x8 vb = *(const f16x8*)&Vs[cur][vrow * 64 + 8 * ((lc + 4 * s2) ^ (vrow & 7))];
                o[dj] = __builtin_amdgcn_mfma_f32_16x16x32_f16(pa, vb, o[dj], 0, 0, 0);
            }
        }
        __builtin_amdgcn_s_setprio(0);

        asm volatile("" ::: "memory");
        __builtin_amdgcn_s_barrier();
        if (kt + 2 < nkt) {
            FSTAGE(cur, kt + 2)
            asm volatile("s_waitcnt vmcnt(4)" ::: "memory");
        } else if (kt + 1 < nkt) {
            asm volatile("s_waitcnt vmcnt(0)" ::: "memory");
        }
        __builtin_amdgcn_s_barrier();
        cur ^= 1;
    }
#undef FSTAGE

#pragma unroll
    for (int dj = 0; dj < 4; dj++)
#pragma unroll
        for (int r = 0; r < 4; r++) {
            float v = o[dj][r] / lrun[r];
            attn[(size_t)(q0 + w * 16 + lc * 4 + r) * EE + h * 64 + dj * 16 + lr] = (f16)v;
        }
}

// ---------------- host launch ----------------
extern "C" void kernel_launch(void* const* d_in, const int* in_sizes, int n_in,
                              void* d_out, int out_size, void* d_ws, size_t ws_size,
                              hipStream_t stream) {
    const int*   ids  = (const int*)d_in[0];
    const float* emb  = (const float*)d_in[2];
    const float* Wq   = (const float*)d_in[3];
    const float* bq   = (const float*)d_in[4];
    const float* Wk   = (const float*)d_in[5];
    const float* bk   = (const float*)d_in[6];
    const float* Wv   = (const float*)d_in[7];
    const float* bv   = (const float*)d_in[8];
    const float* W1   = (const float*)d_in[9];
    const float* b1   = (const float*)d_in[10];
    const float* W2   = (const float*)d_in[11];
    const float* b2   = (const float*)d_in[12];
    const float* Wout = (const float*)d_in[13];
    float* out = (float*)d_out;

    char* p = (char*)d_ws;
    f16* xh    = (f16*)p; p += (size_t)SS * EE * 2;        // 4 MB
    f16* qkvh  = (f16*)p; p += (size_t)SS * 3 * EE * 2;    // 12 MB
    f16* vt    = (f16*)p; p += (size_t)EE * SS * 2;        // 4 MB
    f16* attn  = (f16*)p; p += (size_t)SS * EE * 2;        // 4 MB
    f16* h1    = (f16*)p; p += (size_t)SS * FF * 2;        // 16 MB
    f16* wqkvt = (f16*)p; p += (size_t)3 * EE * EE * 2;    // 6 MB
    f16* w1t   = (f16*)p; p += (size_t)FF * EE * 2;        // 8 MB
    f16* w2t   = (f16*)p; p += (size_t)EE * FF * 2;        // 8 MB
    f16* woutt = (f16*)p; p += (size_t)NV * EE * 2;        // 64 MB
    float* part = (float*)p; p += (size_t)4 * SS * EE * 4; // 32 MB
    float* bqkv = (float*)p; p += 3 * EE * 4;

    k_embed<<<SS, 256, 0, stream>>>(ids, emb, xh);

    for (int l = 0; l < NL; l++) {
        k_trW<<<2817, 256, 0, stream>>>(
            Wq + (size_t)l * EE * EE, Wk + (size_t)l * EE * EE, Wv + (size_t)l * EE * EE,
            W1 + (size_t)l * EE * FF, W2 + (size_t)l * FF * EE,
            bq + l * EE, bk + l * EE, bv + l * EE,
            wqkvt, w1t, w2t, bqkv);

        // QKV: [2048,1024] x [3072,1024]^T -> qkvh (Q,K) + vt (V^T). grid 8*24=192
        k_gemm<256, 128, 1><<<8 * 24, 512, 0, stream>>>(
            xh, wqkvt, bqkv, qkvh, nullptr, vt, SS, 3 * EE, EE, EE, 8, 24, 1, CS, 1.0f, 0);

        k_flash<<<dim3(NH, SS / 64), 256, 0, stream>>>(qkvh, vt, attn);

        // FFN1 + relu: grid 8*32=256
        k_gemm<256, 128, 2><<<8 * 32, 512, 0, stream>>>(
            attn, w1t, b1 + (size_t)l * FF, h1, nullptr, nullptr, SS, FF, EE, EE, 8, 32, 1, CS, 1.0f, 1);

        // FFN2 split-K=4: grid 8*8*4=256
        k_gemm<256, 128, 3><<<8 * 8 * 4, 512, 0, stream>>>(
            h1, w2t, nullptr, nullptr, part, nullptr, SS, EE, FF, FF / 4, 8, 8, 4, 0.0f, 1.0f, 0);
        k_combine4<<<SS * EE / 1024, 256, 0, stream>>>(part, b2 + (size_t)l * EE, xh);
    }

    // logits: [2048,1024] x [32000,1024]^T -> fp32 out (32x32 MFMA). grid 8*125=1000
    k_trOut<<<8000, 256, 0, stream>>>(Wout, woutt);
    k_gemm32<<<8 * 125, 512, 0, stream>>>(xh, woutt, out, NV, EE, 8, 125, INV_CS);
}

// Round 8
// 1523.007 us; speedup vs baseline: 1.2823x; 1.0113x over previous
//
#include <hip/hip_runtime.h>
#include <hip/hip_fp16.h>

// StackedAttentionModel: 8-layer transformer fwd, S=2048 E=1024 H=16 D=64 F=4096 V=32000.
// fp16 MFMA (fp32 accum), global activation scale CS=2^12 folded out exactly.
// R8: logits on m201-style 4-phase 256^2 schedule: per-phase {ds_read quadrant; stage
//     dead half-tile of tt+2 into live buffer; barrier; 16 MFMA; barrier}, vmcnt(8) once
//     per K-tile. Region-death proof: A c0/c2 dead after P0, B dead after P1, A c1/c3
//     dead after P2. Layer GEMMs/flash unchanged (isolate the schedule variable).

#define SS 2048
#define EE 1024
#define NH 16
#define FF 4096
#define NV 32000
#define NL 8

typedef _Float16 f16;
typedef _Float16 f16x8 __attribute__((ext_vector_type(8)));
typedef _Float16 f16x4 __attribute__((ext_vector_type(4)));
typedef float f32x4 __attribute__((ext_vector_type(4)));

#define CS 4096.0f          // 2^12 activation scale
#define INV_CS 0.000244140625f
#define SCORE_SCALE 7.450580596923828e-09f  // 1/(8*CS^2) = 2^-27

__device__ __forceinline__ void gload16(const void* g, void* lds) {
    __builtin_amdgcn_global_load_lds(
        (const __attribute__((address_space(1))) unsigned int*)g,
        (__attribute__((address_space(3))) unsigned int*)lds, 16, 0, 0);
}

#define BAR do { asm volatile("" ::: "memory"); __builtin_amdgcn_s_barrier(); } while (0)

// ---------------- embedding gather (fp32 -> fp16 * CS) ----------------
__global__ void k_embed(const int* __restrict__ ids, const float* __restrict__ emb,
                        f16* __restrict__ xh) {
    int s = blockIdx.x;
    int e = threadIdx.x * 4;
    const float4 v = *(const float4*)&emb[(size_t)ids[s] * EE + e];
    f16x4 h;
    h[0] = (f16)(v.x * CS); h[1] = (f16)(v.y * CS);
    h[2] = (f16)(v.z * CS); h[3] = (f16)(v.w * CS);
    *(f16x4*)&xh[(size_t)s * EE + e] = h;
}

// ---------------- 64x64 transpose tile: fp32 in -> fp16 out ----------------
__device__ __forceinline__ void tr64(const float* __restrict__ in, f16* __restrict__ out,
                                     int ldi, int ldo, int bx, int by) {
    __shared__ float tl[64][65];
    const int tx = threadIdx.x & 15, ty = threadIdx.x >> 4;
#pragma unroll
    for (int i = 0; i < 4; i++) {
        float4 v = *(const float4*)&in[(size_t)(by + ty * 4 + i) * ldi + bx + tx * 4];
        tl[ty * 4 + i][tx * 4 + 0] = v.x;
        tl[ty * 4 + i][tx * 4 + 1] = v.y;
        tl[ty * 4 + i][tx * 4 + 2] = v.z;
        tl[ty * 4 + i][tx * 4 + 3] = v.w;
    }
    __syncthreads();
#pragma unroll
    for (int i = 0; i < 4; i++) {
        f16x4 h;
#pragma unroll
        for (int j = 0; j < 4; j++) h[j] = (f16)tl[tx * 4 + j][ty * 4 + i];
        *(f16x4*)&out[(size_t)(bx + ty * 4 + i) * ldo + by + tx * 4] = h;
    }
}

// fused per-layer weight transposes + bias concat (grid 2817, 256 thr)
__global__ void k_trW(const float* __restrict__ Wq, const float* __restrict__ Wk,
                      const float* __restrict__ Wv, const float* __restrict__ W1,
                      const float* __restrict__ W2,
                      const float* __restrict__ bq, const float* __restrict__ bk,
                      const float* __restrict__ bv,
                      f16* __restrict__ wqkvt, f16* __restrict__ w1t,
                      f16* __restrict__ w2t, float* __restrict__ bqkv) {
    int b = blockIdx.x;
    if (b == 2816) {
        int i = threadIdx.x;
#pragma unroll
        for (int j = 0; j < 12; j++) {
            int idx = j * 256 + i;
            bqkv[idx] = idx < EE ? bq[idx] : (idx < 2 * EE ? bk[idx - EE] : bv[idx - 2 * EE]);
        }
        return;
    }
    if (b < 768) {
        int s = b >> 8, t2 = b & 255;
        tr64(s == 0 ? Wq : (s == 1 ? Wk : Wv), wqkvt + (size_t)s * EE * EE,
             EE, EE, (t2 & 15) * 64, (t2 >> 4) * 64);
    } else if (b < 1792) {
        int t2 = b - 768;
        tr64(W1, w1t, FF, EE, (t2 & 63) * 64, (t2 >> 6) * 64);
    } else {
        int t2 = b - 1792;
        tr64(W2, w2t, EE, FF, (t2 & 15) * 64, (t2 >> 4) * 64);
    }
}

// Wout [1024][32000] -> woutt [32000][1024] (grid 8000, 256 thr)
__global__ void k_trOut(const float* __restrict__ in, f16* __restrict__ out) {
    int b = blockIdx.x;
    tr64(in, out, NV, EE, (b % 500) * 64, (b / 500) * 64);
}

// split-K=4 combiner
__global__ void k_combine4(const float* __restrict__ part, const float* __restrict__ bias,
                           f16* __restrict__ out) {
    const size_t sz = (size_t)SS * EE;
    int i = (blockIdx.x * 256 + threadIdx.x) * 4;
    float4 a = *(const float4*)&part[i];
    float4 b = *(const float4*)&part[i + sz];
    float4 c = *(const float4*)&part[i + 2 * sz];
    float4 d = *(const float4*)&part[i + 3 * sz];
    float4 bb = *(const float4*)&bias[i & (EE - 1)];
    f16x4 h;
    h[0] = (f16)(a.x + b.x + c.x + d.x + bb.x * CS);
    h[1] = (f16)(a.y + b.y + c.y + d.y + bb.y * CS);
    h[2] = (f16)(a.z + b.z + c.z + d.z + bb.z * CS);
    h[3] = (f16)(a.w + b.w + c.w + d.w + bb.w * CS);
    *(f16x4*)&out[i] = h;
}

// ================= layer GEMM (R3 schedule, unchanged) =================
template<int BM, int BN, int TAG>
__global__ __launch_bounds__((BM == 128) ? 256 : 512, 2) void k_gemm(
    const f16* __restrict__ A, const f16* __restrict__ B,
    const float* __restrict__ bias, f16* __restrict__ Ch, float* __restrict__ Cf,
    f16* __restrict__ VtOut,
    int M, int N, int Kstride, int Ksub, int nm, int nn, int kch,
    float bscale, float oscale, int relu) {
    constexpr int WR = (BM == 256) ? ((BN == 256) ? 2 : 4) : 2;
    constexpr int WC = (BN == 256) ? 4 : 2;
    constexpr int NW = WR * WC;
    constexpr int THREADS = NW * 64;
    constexpr int MR = BM / WR / 16;
    constexpr int RPC = THREADS / 8;
    constexpr int ACALLS = BM / RPC;
    constexpr int BCALLS = BN / RPC;
    constexpr int LPT = ACALLS + BCALLS;

    __shared__ f16 As[2][BM * 64];
    __shared__ f16 Bs[2][BN * 64];

    const int t = threadIdx.x;
    const int l = t & 63, w = t >> 6;
    const int lr = l & 15, lc = l >> 4;

    const int nwg = nm * nn * kch;
    const int q8 = nwg >> 3, r8 = nwg & 7;
    const int xcd = blockIdx.x & 7, lid = blockIdx.x >> 3;
    const int wgid = (xcd < r8 ? xcd * (q8 + 1) : r8 * (q8 + 1) + (xcd - r8) * q8) + lid;
    const int kc = wgid / (nm * nn);
    const int rem = wgid - kc * (nm * nn);
    const int m0 = (rem % nm) * BM, n0 = (rem / nm) * BN;

    const f16* Ab = A + (size_t)kc * Ksub;
    const f16* Bb = B + (size_t)kc * Ksub;
    float* Cfb = Cf ? Cf + (size_t)kc * M * N : nullptr;

    const int wr = w / WC, wc = w % WC;

    f32x4 acc[MR][4] = {};

    const int srow = t >> 3;
    const int scol = 8 * ((t & 7) ^ (srow & 7));
    const int NT = Ksub / 64;

#define STAGE(bb, tt_) { \
    const size_t kof = (size_t)(tt_) * 64 + scol; \
    _Pragma("unroll") \
    for (int c = 0; c < ACALLS; c++) \
        gload16(Ab + (size_t)(m0 + c * RPC + srow) * Kstride + kof, \
                (char*)As[bb] + c * (RPC * 128) + w * 1024); \
    _Pragma("unroll") \
    for (int c = 0; c < BCALLS; c++) \
        gload16(Bb + (size_t)(n0 + c * RPC + srow) * Kstride + kof, \
                (char*)Bs[bb] + c * (RPC * 128) + w * 1024); }

    STAGE(0, 0)
    STAGE(1, 1)
    asm volatile("s_waitcnt vmcnt(%0)" :: "n"(LPT) : "memory");
    BAR;

    int cur = 0;
    for (int tt = 0; tt < NT; ++tt) {
        const f16* pA = As[cur];
        const f16* pB = Bs[cur];
#pragma unroll
        for (int ks = 0; ks < 2; ks++) {
            f16x8 af[MR], bf[4];
#pragma unroll
            for (int m = 0; m < MR; m++) {
                const int row = wr * (MR * 16) + m * 16 + lr;
                af[m] = *(const f16x8*)&pA[row * 64 + 8 * ((ks * 4 + lc) ^ (row & 7))];
            }
#pragma unroll
            for (int n = 0; n < 4; n++) {
                const int row = wc * 64 + n * 16 + lr;
                bf[n] = *(const f16x8*)&pB[row * 64 + 8 * ((ks * 4 + lc) ^ (row & 7))];
            }
            __builtin_amdgcn_s_setprio(1);
#pragma unroll
            for (int m = 0; m < MR; m++)
#pragma unroll
                for (int n = 0; n < 4; n++)
                    acc[m][n] = __builtin_amdgcn_mfma_f32_16x16x32_f16(af[m], bf[n], acc[m][n], 0, 0, 0);
            __builtin_amdgcn_s_setprio(0);
        }
        BAR;
        if (tt + 2 < NT) {
            STAGE(cur, tt + 2)
            asm volatile("s_waitcnt vmcnt(%0)" :: "n"(LPT) : "memory");
        } else if (tt + 1 < NT) {
            asm volatile("s_waitcnt vmcnt(0)" ::: "memory");
        }
        BAR;
        cur ^= 1;
    }
#undef STAGE

#pragma unroll
    for (int m = 0; m < MR; m++)
#pragma unroll
        for (int n = 0; n < 4; n++) {
            const int row0 = m0 + wr * (MR * 16) + m * 16 + lc * 4;
            const int col = n0 + wc * 64 + n * 16 + lr;
            float v[4];
#pragma unroll
            for (int r = 0; r < 4; r++) {
                v[r] = acc[m][n][r];
                if (bias) v[r] += bias[col] * bscale;
                if (relu) v[r] = fmaxf(v[r], 0.0f);
            }
            if (VtOut && col >= 2 * EE) {
                f16x4 h4;
#pragma unroll
                for (int r = 0; r < 4; r++) h4[r] = (f16)v[r];
                *(f16x4*)&VtOut[(size_t)(col - 2 * EE) * SS + row0] = h4;
            } else if (Ch) {
#pragma unroll
                for (int r = 0; r < 4; r++)
                    Ch[(size_t)(row0 + r) * N + col] = (f16)v[r];
            } else {
#pragma unroll
                for (int r = 0; r < 4; r++)
                    Cfb[(size_t)(row0 + r) * N + col] = v[r] * oscale;
            }
        }
}

// ================= logits: 256^2 GEMM, m201-style 4-phase schedule =================
// 8 waves 2x4, wave tile 128x64 (MR=8), 16x16x32 MFMA. BK=64, NT=K/64.
// Phase -> MFMA quadrant / ds_reads / stage (tile tt+2, into the live buffer's DEAD rows):
//   P0: quad (m0-3, n0-1): 12 ds_read (A m0-3 ks0-1, B n0-1 ks0-1); no stage
//   P1: quad (m0-3, n2-3): 4 ds_read (B n2-3);         stage A rows 0-63,128-191 (dead after P0)
//   P2: quad (m4-7, n0-1): 8 ds_read (A m4-7);         stage B all rows     (dead after P1)
//   P3: quad (m4-7, n2-3): 0 ds_read;                  stage A rows 64-127,192-255 (dead after P2)
//       + vmcnt(8) (= tt+2's 8 loads in flight; waits tt+1) before barrier.
__global__ __launch_bounds__(512, 2) void k_gemm4p(
    const f16* __restrict__ A, const f16* __restrict__ B, float* __restrict__ Cf,
    int N, int K, int nm, int nn, float oscale) {
    __shared__ f16 As[2][256 * 64];
    __shared__ f16 Bs[2][256 * 64];
    const int t = threadIdx.x;
    const int l = t & 63, w = t >> 6;
    const int lr = l & 15, lc = l >> 4;

    const int nwg = nm * nn;
    const int q8 = nwg >> 3, r8 = nwg & 7;
    const int xcd = blockIdx.x & 7, lid = blockIdx.x >> 3;
    const int wgid = (xcd < r8 ? xcd * (q8 + 1) : r8 * (q8 + 1) + (xcd - r8) * q8) + lid;
    const int m0 = (wgid % nm) * 256, n0 = (wgid / nm) * 256;

    const int wr = w >> 2, wc = w & 3;

    f32x4 acc[8][4] = {};
    f16x8 aF[2][4], bF[2][4];

    const int srow = t >> 3;                 // 0..63
    const int scol = 8 * ((t & 7) ^ (srow & 7));
    const int NT = K / 64;

    // one gload call = rows c*64..c*64+63 of A or B (1 load/thread)
#define SG_A(bb, tt_, c) \
    gload16(A + (size_t)(m0 + (c) * 64 + srow) * K + (size_t)(tt_) * 64 + scol, \
            (char*)As[bb] + (c) * 8192 + w * 1024);
#define SG_B(bb, tt_, c) \
    gload16(B + (size_t)(n0 + (c) * 64 + srow) * K + (size_t)(tt_) * 64 + scol, \
            (char*)Bs[bb] + (c) * 8192 + w * 1024);

#define LDA_HALF(pA_, mh) { _Pragma("unroll") \
    for (int ks = 0; ks < 2; ks++) _Pragma("unroll") \
    for (int m = 0; m < 4; m++) { \
        const int row = wr * 128 + ((mh) * 4 + m) * 16 + lr; \
        aF[ks][m] = *(const f16x8*)&pA_[row * 64 + 8 * ((ks * 4 + lc) ^ (row & 7))]; } }

#define LDB_PAIR(pB_, nb) { _Pragma("unroll") \
    for (int ks = 0; ks < 2; ks++) _Pragma("unroll") \
    for (int j = 0; j < 2; j++) { \
        const int row = wc * 64 + ((nb) + j) * 16 + lr; \
        bF[ks][(nb) + j] = *(const f16x8*)&pB_[row * 64 + 8 * ((ks * 4 + lc) ^ (row & 7))]; } }

#define PH_MMA(mb, nb) { __builtin_amdgcn_s_setprio(1); \
    _Pragma("unroll") for (int ks = 0; ks < 2; ks++) \
    _Pragma("unroll") for (int m = 0; m < 4; m++) \
    _Pragma("unroll") for (int j = 0; j < 2; j++) \
        acc[(mb) + m][(nb) + j] = __builtin_amdgcn_mfma_f32_16x16x32_f16( \
            aF[ks][m], bF[ks][(nb) + j], acc[(mb) + m][(nb) + j], 0, 0, 0); \
    __builtin_amdgcn_s_setprio(0); }

    // prologue: stage tiles 0 and 1 fully
#pragma unroll
    for (int c = 0; c < 4; c++) { SG_A(0, 0, c) SG_B(0, 0, c) }
#pragma unroll
    for (int c = 0; c < 4; c++) { SG_A(1, 1, c) SG_B(1, 1, c) }
    asm volatile("s_waitcnt vmcnt(8)" ::: "memory");   // tile 0 landed
    BAR;

    int cur = 0;
    for (int tt = 0; tt < NT; ++tt) {
        const f16* pA = As[cur];
        const f16* pB = Bs[cur];
        const bool pre = (tt + 2 < NT);

        // P0
        LDA_HALF(pA, 0)
        LDB_PAIR(pB, 0)
        BAR;
        PH_MMA(0, 0)
        BAR;

        // P1
        LDB_PAIR(pB, 2)
        if (pre) { SG_A(cur, tt + 2, 0) SG_A(cur, tt + 2, 2) }
        BAR;
        PH_MMA(0, 2)
        BAR;

        // P2
        LDA_HALF(pA, 1)
        if (pre) { SG_B(cur, tt + 2, 0) SG_B(cur, tt + 2, 1)
                   SG_B(cur, tt + 2, 2) SG_B(cur, tt + 2, 3) }
        BAR;
        PH_MMA(4, 0)
        BAR;

        // P3
        if (pre) {
            SG_A(cur, tt + 2, 1) SG_A(cur, tt + 2, 3)
            asm volatile("s_waitcnt vmcnt(8)" ::: "memory");   // tile tt+1 landed
        } else if (tt + 1 < NT) {
            asm volatile("s_waitcnt vmcnt(0)" ::: "memory");
        }
        BAR;
        PH_MMA(4, 2)
        BAR;

        cur ^= 1;
    }
#undef SG_A
#undef SG_B
#undef LDA_HALF
#undef LDB_PAIR
#undef PH_MMA

    // epilogue: C/D col=lane&15, row=(lane>>4)*4+reg
#pragma unroll
    for (int m = 0; m < 8; m++)
#pragma unroll
        for (int n = 0; n < 4; n++) {
            const int row0 = m0 + wr * 128 + m * 16 + lc * 4;
            const int col = n0 + wc * 64 + n * 16 + lr;
#pragma unroll
            for (int r = 0; r < 4; r++)
                Cf[(size_t)(row0 + r) * N + col] = acc[m][n][r] * oscale;
        }
}

// ---------------- flash attention (counted-vmcnt pipeline, heavy-first) ----------------
__global__ __launch_bounds__(256) void k_flash(
    const f16* __restrict__ qkv, const f16* __restrict__ vt, f16* __restrict__ attn) {
    __shared__ f16 Ks[2][4096];
    __shared__ f16 Vs[2][4096];
    __shared__ f16 Ps[4096];
    const int h = blockIdx.x;
    const int qb = (SS / 64 - 1) - blockIdx.y;
    const int t = threadIdx.x, l = t & 63, w = t >> 6;
    const int lr = l & 15, lc = l >> 4;
    const int q0 = qb * 64;
    const int qrow = q0 + w * 16 + lr;

    f16x8 qf0 = *(const f16x8*)&qkv[(size_t)qrow * 3072 + h * 64 + lc * 8];
    f16x8 qf1 = *(const f16x8*)&qkv[(size_t)qrow * 3072 + h * 64 + 32 + lc * 8];

    f32x4 o[4] = {};
    float mrun[4], lrun[4];
#pragma unroll
    for (int r = 0; r < 4; r++) { mrun[r] = -__builtin_inff(); lrun[r] = 0.0f; }

    const int krow = t >> 3;
    const int kscol = 8 * ((t & 7) ^ (krow & 7));
    const f16* gK = qkv + EE + h * 64;
    const f16* gV = vt + (size_t)(h * 64) * SS;
    f16* Pw = &Ps[w * 16 * 64];
    const int psw = (lr & 7) << 4;

#define FSTAGE(bb, kt_) { \
    char* dK = (char*)Ks[bb] + w * 1024; \
    char* dV = (char*)Vs[bb] + w * 1024; \
    gload16(gK + (size_t)((kt_) * 64 + krow) * 3072 + kscol, dK); \
    gload16(gK + (size_t)((kt_) * 64 + krow + 32) * 3072 + kscol, dK + 4096); \
    gload16(gV + (size_t)krow * SS + (kt_) * 64 + kscol, dV); \
    gload16(gV + (size_t)(krow + 32) * SS + (kt_) * 64 + kscol, dV + 4096); }

    const int nkt = qb + 1;
    FSTAGE(0, 0)
    FSTAGE(1, 1)
    asm volatile("s_waitcnt vmcnt(4)" ::: "memory");
    __builtin_amdgcn_s_barrier();

    int cur = 0;
    for (int kt = 0; kt < nkt; kt++) {
        f32x4 sc[4];
        __builtin_amdgcn_s_setprio(1);
#pragma unroll
        for (int kj = 0; kj < 4; kj++) {
            const int krw = kj * 16 + lr;
            const int sw = krw & 7;
            f16x8 kb0 = *(const f16x8*)&Ks[cur][krw * 64 + 8 * (lc ^ sw)];
            f16x8 kb1 = *(const f16x8*)&Ks[cur][krw * 64 + 8 * ((lc + 4) ^ sw)];
            f32x4 z = {};
            z = __builtin_amdgcn_mfma_f32_16x16x32_f16(qf0, kb0, z, 0, 0, 0);
            z = __builtin_amdgcn_mfma_f32_16x16x32_f16(qf1, kb1, z, 0, 0, 0);
            sc[kj] = z;
        }
        __builtin_amdgcn_s_setprio(0);

        const bool diag = (kt == qb);
#pragma unroll
        for (int kj = 0; kj < 4; kj++)
#pragma unroll
            for (int r = 0; r < 4; r++) {
                float v = sc[kj][r] * SCORE_SCALE;
                if (diag) {
                    int qq = w * 16 + lc * 4 + r;
                    int kk = kj * 16 + lr;
                    if (kk > qq) v = -__builtin_inff();
                }
                sc[kj][r] = v;
            }

#pragma unroll
        for (int r = 0; r < 4; r++) {
            float mt = fmaxf(fmaxf(sc[0][r], sc[1][r]), fmaxf(sc[2][r], sc[3][r]));
            mt = fmaxf(mt, __shfl_xor(mt, 1));
            mt = fmaxf(mt, __shfl_xor(mt, 2));
            mt = fmaxf(mt, __shfl_xor(mt, 4));
            mt = fmaxf(mt, __shfl_xor(mt, 8));
            float mnew = fmaxf(mrun[r], mt);
            float alpha = __expf(mrun[r] - mnew);
            float psum = 0.0f;
#pragma unroll
            for (int kj = 0; kj < 4; kj++) {
                float p = __expf(sc[kj][r] - mnew);
                sc[kj][r] = p;
                psum += p;
            }
            psum += __shfl_xor(psum, 1);
            psum += __shfl_xor(psum, 2);
            psum += __shfl_xor(psum, 4);
            psum += __shfl_xor(psum, 8);
            lrun[r] = lrun[r] * alpha + psum;
            mrun[r] = mnew;
#pragma unroll
            for (int dj = 0; dj < 4; dj++) o[dj][r] *= alpha;
        }

#pragma unroll
        for (int kj = 0; kj < 4; kj++)
#pragma unroll
            for (int r = 0; r < 4; r++) {
                int prow = lc * 4 + r;
                int pb = prow * 128 + ((kj * 16 + lr) * 2 ^ ((prow & 7) << 4));
                *(f16*)((char*)Pw + pb) = (f16)sc[kj][r];
            }

        __builtin_amdgcn_s_setprio(1);
#pragma unroll
        for (int s2 = 0; s2 < 2; s2++) {
            f16x8 pa = *(const f16x8*)((const char*)Pw + lr * 128 + (((lc + 4 * s2) * 16) ^ psw));
#pragma unroll
            for (int dj = 0; dj < 4; dj++) {
                const int vrow = dj * 16 + lr;
                f16x8 vb = *(const f16x8*)&Vs[cur][vrow * 64 + 8 * ((lc + 4 * s2) ^ (vrow & 7))];
                o[dj] = __builtin_amdgcn_mfma_f32_16x16x32_f16(pa, vb, o[dj], 0, 0, 0);
            }
        }
        __builtin_amdgcn_s_setprio(0);

        asm volatile("" ::: "memory");
        __builtin_amdgcn_s_barrier();
        if (kt + 2 < nkt) {
            FSTAGE(cur, kt + 2)
            asm volatile("s_waitcnt vmcnt(4)" ::: "memory");
        } else if (kt + 1 < nkt) {
            asm volatile("s_waitcnt vmcnt(0)" ::: "memory");
        }
        __builtin_amdgcn_s_barrier();
        cur ^= 1;
    }
#undef FSTAGE

#pragma unroll
    for (int dj = 0; dj < 4; dj++)
#pragma unroll
        for (int r = 0; r < 4; r++) {
            float v = o[dj][r] / lrun[r];
            attn[(size_t)(q0 + w * 16 + lc * 4 + r) * EE + h * 64 + dj * 16 + lr] = (f16)v;
        }
}

// ---------------- host launch ----------------
extern "C" void kernel_launch(void* const* d_in, const int* in_sizes, int n_in,
                              void* d_out, int out_size, void* d_ws, size_t ws_size,
                              hipStream_t stream) {
    const int*   ids  = (const int*)d_in[0];
    const float* emb  = (const float*)d_in[2];
    const float* Wq   = (const float*)d_in[3];
    const float* bq   = (const float*)d_in[4];
    const float* Wk   = (const float*)d_in[5];
    const float* bk   = (const float*)d_in[6];
    const float* Wv   = (const float*)d_in[7];
    const float* bv   = (const float*)d_in[8];
    const float* W1   = (const float*)d_in[9];
    const float* b1   = (const float*)d_in[10];
    const float* W2   = (const float*)d_in[11];
    const float* b2   = (const float*)d_in[12];
    const float* Wout = (const float*)d_in[13];
    float* out = (float*)d_out;

    char* p = (char*)d_ws;
    f16* xh    = (f16*)p; p += (size_t)SS * EE * 2;        // 4 MB
    f16* qkvh  = (f16*)p; p += (size_t)SS * 3 * EE * 2;    // 12 MB
    f16* vt    = (f16*)p; p += (size_t)EE * SS * 2;        // 4 MB
    f16* attn  = (f16*)p; p += (size_t)SS * EE * 2;        // 4 MB
    f16* h1    = (f16*)p; p += (size_t)SS * FF * 2;        // 16 MB
    f16* wqkvt = (f16*)p; p += (size_t)3 * EE * EE * 2;    // 6 MB
    f16* w1t   = (f16*)p; p += (size_t)FF * EE * 2;        // 8 MB
    f16* w2t   = (f16*)p; p += (size_t)EE * FF * 2;        // 8 MB
    f16* woutt = (f16*)p; p += (size_t)NV * EE * 2;        // 64 MB
    float* part = (float*)p; p += (size_t)4 * SS * EE * 4; // 32 MB
    float* bqkv = (float*)p; p += 3 * EE * 4;

    k_embed<<<SS, 256, 0, stream>>>(ids, emb, xh);

    for (int l = 0; l < NL; l++) {
        k_trW<<<2817, 256, 0, stream>>>(
            Wq + (size_t)l * EE * EE, Wk + (size_t)l * EE * EE, Wv + (size_t)l * EE * EE,
            W1 + (size_t)l * EE * FF, W2 + (size_t)l * FF * EE,
            bq + l * EE, bk + l * EE, bv + l * EE,
            wqkvt, w1t, w2t, bqkv);

        // QKV: [2048,1024] x [3072,1024]^T -> qkvh (Q,K) + vt (V^T). grid 8*24=192
        k_gemm<256, 128, 1><<<8 * 24, 512, 0, stream>>>(
            xh, wqkvt, bqkv, qkvh, nullptr, vt, SS, 3 * EE, EE, EE, 8, 24, 1, CS, 1.0f, 0);

        k_flash<<<dim3(NH, SS / 64), 256, 0, stream>>>(qkvh, vt, attn);

        // FFN1 + relu: grid 8*32=256
        k_gemm<256, 128, 2><<<8 * 32, 512, 0, stream>>>(
            attn, w1t, b1 + (size_t)l * FF, h1, nullptr, nullptr, SS, FF, EE, EE, 8, 32, 1, CS, 1.0f, 1);

        // FFN2 split-K=4: grid 8*8*4=256
        k_gemm<256, 128, 3><<<8 * 8 * 4, 512, 0, stream>>>(
            h1, w2t, nullptr, nullptr, part, nullptr, SS, EE, FF, FF / 4, 8, 8, 4, 0.0f, 1.0f, 0);
        k_combine4<<<SS * EE / 1024, 256, 0, stream>>>(part, b2 + (size_t)l * EE, xh);
    }

    // logits: [2048,1024] x [32000,1024]^T -> fp32 out. 4-phase schedule, grid 8*125=1000
    k_trOut<<<8000, 256, 0, stream>>>(Wout, woutt);
    k_gemm4p<<<8 * 125, 512, 0, stream>>>(xh, woutt, out, NV, EE, 8, 125, INV_CS);
}

// Round 9
// 1440.047 us; speedup vs baseline: 1.3561x; 1.0576x over previous
//
#include <hip/hip_runtime.h>
#include <hip/hip_fp16.h>

// StackedAttentionModel: 8-layer transformer fwd, S=2048 E=1024 H=16 D=64 F=4096 V=32000.
// fp16 MFMA (fp32 accum), global activation scale CS=2^12 folded out exactly.
// R9: flash rework (isolated): KVBLK=128 (half the loop/barrier/reduction overhead),
//     heavy+light qb pairing (per-CU load balance), defer-max T13 + exp2-domain softmax.
//     Logits 4-phase (R8 win) and layer GEMMs unchanged.

#define SS 2048
#define EE 1024
#define NH 16
#define FF 4096
#define NV 32000
#define NL 8

typedef _Float16 f16;
typedef _Float16 f16x8 __attribute__((ext_vector_type(8)));
typedef _Float16 f16x4 __attribute__((ext_vector_type(4)));
typedef float f32x4 __attribute__((ext_vector_type(4)));

#define CS 4096.0f          // 2^12 activation scale
#define INV_CS 0.000244140625f
#define SCORE_SCALE 7.450580596923828e-09f          // 1/(8*CS^2) = 2^-27
#define SCORE_SCALE2 1.0748631e-08f                 // 2^-27 * log2(e)  (exp2-domain softmax)

__device__ __forceinline__ void gload16(const void* g, void* lds) {
    __builtin_amdgcn_global_load_lds(
        (const __attribute__((address_space(1))) unsigned int*)g,
        (__attribute__((address_space(3))) unsigned int*)lds, 16, 0, 0);
}

#define BAR do { asm volatile("" ::: "memory"); __builtin_amdgcn_s_barrier(); } while (0)

// ---------------- embedding gather (fp32 -> fp16 * CS) ----------------
__global__ void k_embed(const int* __restrict__ ids, const float* __restrict__ emb,
                        f16* __restrict__ xh) {
    int s = blockIdx.x;
    int e = threadIdx.x * 4;
    const float4 v = *(const float4*)&emb[(size_t)ids[s] * EE + e];
    f16x4 h;
    h[0] = (f16)(v.x * CS); h[1] = (f16)(v.y * CS);
    h[2] = (f16)(v.z * CS); h[3] = (f16)(v.w * CS);
    *(f16x4*)&xh[(size_t)s * EE + e] = h;
}

// ---------------- 64x64 transpose tile: fp32 in -> fp16 out ----------------
__device__ __forceinline__ void tr64(const float* __restrict__ in, f16* __restrict__ out,
                                     int ldi, int ldo, int bx, int by) {
    __shared__ float tl[64][65];
    const int tx = threadIdx.x & 15, ty = threadIdx.x >> 4;
#pragma unroll
    for (int i = 0; i < 4; i++) {
        float4 v = *(const float4*)&in[(size_t)(by + ty * 4 + i) * ldi + bx + tx * 4];
        tl[ty * 4 + i][tx * 4 + 0] = v.x;
        tl[ty * 4 + i][tx * 4 + 1] = v.y;
        tl[ty * 4 + i][tx * 4 + 2] = v.z;
        tl[ty * 4 + i][tx * 4 + 3] = v.w;
    }
    __syncthreads();
#pragma unroll
    for (int i = 0; i < 4; i++) {
        f16x4 h;
#pragma unroll
        for (int j = 0; j < 4; j++) h[j] = (f16)tl[tx * 4 + j][ty * 4 + i];
        *(f16x4*)&out[(size_t)(bx + ty * 4 + i) * ldo + by + tx * 4] = h;
    }
}

// fused per-layer weight transposes + bias concat (grid 2817, 256 thr)
__global__ void k_trW(const float* __restrict__ Wq, const float* __restrict__ Wk,
                      const float* __restrict__ Wv, const float* __restrict__ W1,
                      const float* __restrict__ W2,
                      const float* __restrict__ bq, const float* __restrict__ bk,
                      const float* __restrict__ bv,
                      f16* __restrict__ wqkvt, f16* __restrict__ w1t,
                      f16* __restrict__ w2t, float* __restrict__ bqkv) {
    int b = blockIdx.x;
    if (b == 2816) {
        int i = threadIdx.x;
#pragma unroll
        for (int j = 0; j < 12; j++) {
            int idx = j * 256 + i;
            bqkv[idx] = idx < EE ? bq[idx] : (idx < 2 * EE ? bk[idx - EE] : bv[idx - 2 * EE]);
        }
        return;
    }
    if (b < 768) {
        int s = b >> 8, t2 = b & 255;
        tr64(s == 0 ? Wq : (s == 1 ? Wk : Wv), wqkvt + (size_t)s * EE * EE,
             EE, EE, (t2 & 15) * 64, (t2 >> 4) * 64);
    } else if (b < 1792) {
        int t2 = b - 768;
        tr64(W1, w1t, FF, EE, (t2 & 63) * 64, (t2 >> 6) * 64);
    } else {
        int t2 = b - 1792;
        tr64(W2, w2t, EE, FF, (t2 & 15) * 64, (t2 >> 4) * 64);
    }
}

// Wout [1024][32000] -> woutt [32000][1024] (grid 8000, 256 thr)
__global__ void k_trOut(const float* __restrict__ in, f16* __restrict__ out) {
    int b = blockIdx.x;
    tr64(in, out, NV, EE, (b % 500) * 64, (b / 500) * 64);
}

// split-K=4 combiner
__global__ void k_combine4(const float* __restrict__ part, const float* __restrict__ bias,
                           f16* __restrict__ out) {
    const size_t sz = (size_t)SS * EE;
    int i = (blockIdx.x * 256 + threadIdx.x) * 4;
    float4 a = *(const float4*)&part[i];
    float4 b = *(const float4*)&part[i + sz];
    float4 c = *(const float4*)&part[i + 2 * sz];
    float4 d = *(const float4*)&part[i + 3 * sz];
    float4 bb = *(const float4*)&bias[i & (EE - 1)];
    f16x4 h;
    h[0] = (f16)(a.x + b.x + c.x + d.x + bb.x * CS);
    h[1] = (f16)(a.y + b.y + c.y + d.y + bb.y * CS);
    h[2] = (f16)(a.z + b.z + c.z + d.z + bb.z * CS);
    h[3] = (f16)(a.w + b.w + c.w + d.w + bb.w * CS);
    *(f16x4*)&out[i] = h;
}

// ================= layer GEMM (R3 schedule, unchanged) =================
template<int BM, int BN, int TAG>
__global__ __launch_bounds__((BM == 128) ? 256 : 512, 2) void k_gemm(
    const f16* __restrict__ A, const f16* __restrict__ B,
    const float* __restrict__ bias, f16* __restrict__ Ch, float* __restrict__ Cf,
    f16* __restrict__ VtOut,
    int M, int N, int Kstride, int Ksub, int nm, int nn, int kch,
    float bscale, float oscale, int relu) {
    constexpr int WR = (BM == 256) ? ((BN == 256) ? 2 : 4) : 2;
    constexpr int WC = (BN == 256) ? 4 : 2;
    constexpr int NW = WR * WC;
    constexpr int THREADS = NW * 64;
    constexpr int MR = BM / WR / 16;
    constexpr int RPC = THREADS / 8;
    constexpr int ACALLS = BM / RPC;
    constexpr int BCALLS = BN / RPC;
    constexpr int LPT = ACALLS + BCALLS;

    __shared__ f16 As[2][BM * 64];
    __shared__ f16 Bs[2][BN * 64];

    const int t = threadIdx.x;
    const int l = t & 63, w = t >> 6;
    const int lr = l & 15, lc = l >> 4;

    const int nwg = nm * nn * kch;
    const int q8 = nwg >> 3, r8 = nwg & 7;
    const int xcd = blockIdx.x & 7, lid = blockIdx.x >> 3;
    const int wgid = (xcd < r8 ? xcd * (q8 + 1) : r8 * (q8 + 1) + (xcd - r8) * q8) + lid;
    const int kc = wgid / (nm * nn);
    const int rem = wgid - kc * (nm * nn);
    const int m0 = (rem % nm) * BM, n0 = (rem / nm) * BN;

    const f16* Ab = A + (size_t)kc * Ksub;
    const f16* Bb = B + (size_t)kc * Ksub;
    float* Cfb = Cf ? Cf + (size_t)kc * M * N : nullptr;

    const int wr = w / WC, wc = w % WC;

    f32x4 acc[MR][4] = {};

    const int srow = t >> 3;
    const int scol = 8 * ((t & 7) ^ (srow & 7));
    const int NT = Ksub / 64;

#define STAGE(bb, tt_) { \
    const size_t kof = (size_t)(tt_) * 64 + scol; \
    _Pragma("unroll") \
    for (int c = 0; c < ACALLS; c++) \
        gload16(Ab + (size_t)(m0 + c * RPC + srow) * Kstride + kof, \
                (char*)As[bb] + c * (RPC * 128) + w * 1024); \
    _Pragma("unroll") \
    for (int c = 0; c < BCALLS; c++) \
        gload16(Bb + (size_t)(n0 + c * RPC + srow) * Kstride + kof, \
                (char*)Bs[bb] + c * (RPC * 128) + w * 1024); }

    STAGE(0, 0)
    STAGE(1, 1)
    asm volatile("s_waitcnt vmcnt(%0)" :: "n"(LPT) : "memory");
    BAR;

    int cur = 0;
    for (int tt = 0; tt < NT; ++tt) {
        const f16* pA = As[cur];
        const f16* pB = Bs[cur];
#pragma unroll
        for (int ks = 0; ks < 2; ks++) {
            f16x8 af[MR], bf[4];
#pragma unroll
            for (int m = 0; m < MR; m++) {
                const int row = wr * (MR * 16) + m * 16 + lr;
                af[m] = *(const f16x8*)&pA[row * 64 + 8 * ((ks * 4 + lc) ^ (row & 7))];
            }
#pragma unroll
            for (int n = 0; n < 4; n++) {
                const int row = wc * 64 + n * 16 + lr;
                bf[n] = *(const f16x8*)&pB[row * 64 + 8 * ((ks * 4 + lc) ^ (row & 7))];
            }
            __builtin_amdgcn_s_setprio(1);
#pragma unroll
            for (int m = 0; m < MR; m++)
#pragma unroll
                for (int n = 0; n < 4; n++)
                    acc[m][n] = __builtin_amdgcn_mfma_f32_16x16x32_f16(af[m], bf[n], acc[m][n], 0, 0, 0);
            __builtin_amdgcn_s_setprio(0);
        }
        BAR;
        if (tt + 2 < NT) {
            STAGE(cur, tt + 2)
            asm volatile("s_waitcnt vmcnt(%0)" :: "n"(LPT) : "memory");
        } else if (tt + 1 < NT) {
            asm volatile("s_waitcnt vmcnt(0)" ::: "memory");
        }
        BAR;
        cur ^= 1;
    }
#undef STAGE

#pragma unroll
    for (int m = 0; m < MR; m++)
#pragma unroll
        for (int n = 0; n < 4; n++) {
            const int row0 = m0 + wr * (MR * 16) + m * 16 + lc * 4;
            const int col = n0 + wc * 64 + n * 16 + lr;
            float v[4];
#pragma unroll
            for (int r = 0; r < 4; r++) {
                v[r] = acc[m][n][r];
                if (bias) v[r] += bias[col] * bscale;
                if (relu) v[r] = fmaxf(v[r], 0.0f);
            }
            if (VtOut && col >= 2 * EE) {
                f16x4 h4;
#pragma unroll
                for (int r = 0; r < 4; r++) h4[r] = (f16)v[r];
                *(f16x4*)&VtOut[(size_t)(col - 2 * EE) * SS + row0] = h4;
            } else if (Ch) {
#pragma unroll
                for (int r = 0; r < 4; r++)
                    Ch[(size_t)(row0 + r) * N + col] = (f16)v[r];
            } else {
#pragma unroll
                for (int r = 0; r < 4; r++)
                    Cfb[(size_t)(row0 + r) * N + col] = v[r] * oscale;
            }
        }
}

// ================= logits: 256^2 GEMM, 4-phase schedule (R8, unchanged) =================
__global__ __launch_bounds__(512, 2) void k_gemm4p(
    const f16* __restrict__ A, const f16* __restrict__ B, float* __restrict__ Cf,
    int N, int K, int nm, int nn, float oscale) {
    __shared__ f16 As[2][256 * 64];
    __shared__ f16 Bs[2][256 * 64];
    const int t = threadIdx.x;
    const int l = t & 63, w = t >> 6;
    const int lr = l & 15, lc = l >> 4;

    const int nwg = nm * nn;
    const int q8 = nwg >> 3, r8 = nwg & 7;
    const int xcd = blockIdx.x & 7, lid = blockIdx.x >> 3;
    const int wgid = (xcd < r8 ? xcd * (q8 + 1) : r8 * (q8 + 1) + (xcd - r8) * q8) + lid;
    const int m0 = (wgid % nm) * 256, n0 = (wgid / nm) * 256;

    const int wr = w >> 2, wc = w & 3;

    f32x4 acc[8][4] = {};
    f16x8 aF[2][4], bF[2][4];

    const int srow = t >> 3;
    const int scol = 8 * ((t & 7) ^ (srow & 7));
    const int NT = K / 64;

#define SG_A(bb, tt_, c) \
    gload16(A + (size_t)(m0 + (c) * 64 + srow) * K + (size_t)(tt_) * 64 + scol, \
            (char*)As[bb] + (c) * 8192 + w * 1024);
#define SG_B(bb, tt_, c) \
    gload16(B + (size_t)(n0 + (c) * 64 + srow) * K + (size_t)(tt_) * 64 + scol, \
            (char*)Bs[bb] + (c) * 8192 + w * 1024);

#define LDA_HALF(pA_, mh) { _Pragma("unroll") \
    for (int ks = 0; ks < 2; ks++) _Pragma("unroll") \
    for (int m = 0; m < 4; m++) { \
        const int row = wr * 128 + ((mh) * 4 + m) * 16 + lr; \
        aF[ks][m] = *(const f16x8*)&pA_[row * 64 + 8 * ((ks * 4 + lc) ^ (row & 7))]; } }

#define LDB_PAIR(pB_, nb) { _Pragma("unroll") \
    for (int ks = 0; ks < 2; ks++) _Pragma("unroll") \
    for (int j = 0; j < 2; j++) { \
        const int row = wc * 64 + ((nb) + j) * 16 + lr; \
        bF[ks][(nb) + j] = *(const f16x8*)&pB_[row * 64 + 8 * ((ks * 4 + lc) ^ (row & 7))]; } }

#define PH_MMA(mb, nb) { __builtin_amdgcn_s_setprio(1); \
    _Pragma("unroll") for (int ks = 0; ks < 2; ks++) \
    _Pragma("unroll") for (int m = 0; m < 4; m++) \
    _Pragma("unroll") for (int j = 0; j < 2; j++) \
        acc[(mb) + m][(nb) + j] = __builtin_amdgcn_mfma_f32_16x16x32_f16( \
            aF[ks][m], bF[ks][(nb) + j], acc[(mb) + m][(nb) + j], 0, 0, 0); \
    __builtin_amdgcn_s_setprio(0); }

#pragma unroll
    for (int c = 0; c < 4; c++) { SG_A(0, 0, c) SG_B(0, 0, c) }
#pragma unroll
    for (int c = 0; c < 4; c++) { SG_A(1, 1, c) SG_B(1, 1, c) }
    asm volatile("s_waitcnt vmcnt(8)" ::: "memory");
    BAR;

    int cur = 0;
    for (int tt = 0; tt < NT; ++tt) {
        const f16* pA = As[cur];
        const f16* pB = Bs[cur];
        const bool pre = (tt + 2 < NT);

        LDA_HALF(pA, 0)
        LDB_PAIR(pB, 0)
        BAR;
        PH_MMA(0, 0)
        BAR;

        LDB_PAIR(pB, 2)
        if (pre) { SG_A(cur, tt + 2, 0) SG_A(cur, tt + 2, 2) }
        BAR;
        PH_MMA(0, 2)
        BAR;

        LDA_HALF(pA, 1)
        if (pre) { SG_B(cur, tt + 2, 0) SG_B(cur, tt + 2, 1)
                   SG_B(cur, tt + 2, 2) SG_B(cur, tt + 2, 3) }
        BAR;
        PH_MMA(4, 0)
        BAR;

        if (pre) {
            SG_A(cur, tt + 2, 1) SG_A(cur, tt + 2, 3)
            asm volatile("s_waitcnt vmcnt(8)" ::: "memory");
        } else if (tt + 1 < NT) {
            asm volatile("s_waitcnt vmcnt(0)" ::: "memory");
        }
        BAR;
        PH_MMA(4, 2)
        BAR;

        cur ^= 1;
    }
#undef SG_A
#undef SG_B
#undef LDA_HALF
#undef LDB_PAIR
#undef PH_MMA

#pragma unroll
    for (int m = 0; m < 8; m++)
#pragma unroll
        for (int n = 0; n < 4; n++) {
            const int row0 = m0 + wr * 128 + m * 16 + lc * 4;
            const int col = n0 + wc * 64 + n * 16 + lr;
#pragma unroll
            for (int r = 0; r < 4; r++)
                Cf[(size_t)(row0 + r) * N + col] = acc[m][n][r] * oscale;
        }
}

// ---------------- flash attention: KVBLK=128, defer-max, paired dispatch ----------------
// grid (H, 32). Block 256 = 4 waves x 16 q-rows. K/V tiles [128k][64d] / [64d][128k],
// double-buffered (80KB LDS -> 2 blocks/CU = whole 512-block grid co-resident).
// qb mapping pairs heavy+light on each CU: y<16 -> 31-2y, else 2(y-16) (17+-1 tile-units/CU).
// Softmax in exp2 domain (log2e folded into score scale); T13 defer-max with THR=11 (2^11 bound).
__global__ __launch_bounds__(256) void k_flash(
    const f16* __restrict__ qkv, const f16* __restrict__ vt, f16* __restrict__ attn) {
    __shared__ f16 Ks[2][128 * 64];
    __shared__ f16 Vs[2][64 * 128];
    __shared__ f16 Ps[4 * 16 * 128];
    const int h = blockIdx.x;
    const int y = blockIdx.y;
    const int qb = (y < 16) ? (31 - 2 * y) : (2 * (y - 16));
    const int t = threadIdx.x, l = t & 63, w = t >> 6;
    const int lr = l & 15, lc = l >> 4;
    const int q0 = qb * 64;
    const int qrow = q0 + w * 16 + lr;

    f16x8 qf0 = *(const f16x8*)&qkv[(size_t)qrow * 3072 + h * 64 + lc * 8];
    f16x8 qf1 = *(const f16x8*)&qkv[(size_t)qrow * 3072 + h * 64 + 32 + lc * 8];

    f32x4 o[4] = {};
    float mrun[4], lrun[4];
#pragma unroll
    for (int r = 0; r < 4; r++) { mrun[r] = -__builtin_inff(); lrun[r] = 0.0f; }

    const int krow = t >> 3;                       // K stage: 32 rows (128B) per call
    const int kscol = 8 * ((t & 7) ^ (krow & 7));
    const int vrow = t >> 4;                       // V stage: 16 rows (256B) per call
    const int vscol = 8 * ((t & 15) ^ (vrow & 7));
    const f16* gK = qkv + EE + h * 64;
    const f16* gV = vt + (size_t)(h * 64) * SS;
    f16* Pw = &Ps[w * 16 * 128];
    const int psw = (lr & 7) << 4;

#define FSTAGE(bb, kt_) { \
    _Pragma("unroll") \
    for (int c = 0; c < 4; c++) { \
        gload16(gK + (size_t)((kt_) * 128 + c * 32 + krow) * 3072 + kscol, \
                (char*)Ks[bb] + c * 4096 + w * 1024); \
        gload16(gV + (size_t)(c * 16 + vrow) * SS + (kt_) * 128 + vscol, \
                (char*)Vs[bb] + c * 4096 + w * 1024); } }

    const int nkt = (qb >> 1) + 1;                 // ceil((q0+64)/128)
    FSTAGE(0, 0)
    FSTAGE(1, 1)
    asm volatile("s_waitcnt vmcnt(8)" ::: "memory");
    __builtin_amdgcn_s_barrier();

    int cur = 0;
    for (int kt = 0; kt < nkt; kt++) {
        // QK^T: scores[16q x 128k] per wave
        f32x4 sc[8];
        __builtin_amdgcn_s_setprio(1);
#pragma unroll
        for (int kj = 0; kj < 8; kj++) {
            const int krw = kj * 16 + lr;
            const int sw = krw & 7;
            f16x8 kb0 = *(const f16x8*)&Ks[cur][krw * 64 + 8 * (lc ^ sw)];
            f16x8 kb1 = *(const f16x8*)&Ks[cur][krw * 64 + 8 * ((lc + 4) ^ sw)];
            f32x4 z = {};
            z = __builtin_amdgcn_mfma_f32_16x16x32_f16(qf0, kb0, z, 0, 0, 0);
            z = __builtin_amdgcn_mfma_f32_16x16x32_f16(qf1, kb1, z, 0, 0, 0);
            sc[kj] = z;
        }
        __builtin_amdgcn_s_setprio(0);

        // scale (exp2 domain) + causal mask (only the diagonal-straddling last tile)
        const bool diag = (kt == nkt - 1);
#pragma unroll
        for (int kj = 0; kj < 8; kj++)
#pragma unroll
            for (int r = 0; r < 4; r++) {
                float v = sc[kj][r] * SCORE_SCALE2;
                if (diag) {
                    int kk = kt * 128 + kj * 16 + lr;
                    int qq = q0 + w * 16 + lc * 4 + r;
                    if (kk > qq) v = -__builtin_inff();
                }
                sc[kj][r] = v;
            }

        // row maxes (16-lane groups share a q-row)
        float mt[4];
#pragma unroll
        for (int r = 0; r < 4; r++) {
            float m2 = fmaxf(fmaxf(fmaxf(sc[0][r], sc[1][r]), fmaxf(sc[2][r], sc[3][r])),
                             fmaxf(fmaxf(sc[4][r], sc[5][r]), fmaxf(sc[6][r], sc[7][r])));
            m2 = fmaxf(m2, __shfl_xor(m2, 1));
            m2 = fmaxf(m2, __shfl_xor(m2, 2));
            m2 = fmaxf(m2, __shfl_xor(m2, 4));
            m2 = fmaxf(m2, __shfl_xor(m2, 8));
            mt[r] = m2;
        }
        // T13 defer-max: rescale only when some row grew > 11 (P bounded by 2^11 in fp16)
        bool need = (mt[0] > mrun[0] + 11.0f) || (mt[1] > mrun[1] + 11.0f) ||
                    (mt[2] > mrun[2] + 11.0f) || (mt[3] > mrun[3] + 11.0f);
        if (__any(need)) {
#pragma unroll
            for (int r = 0; r < 4; r++) {
                float mnew = fmaxf(mrun[r], mt[r]);
                float alpha = exp2f(mrun[r] - mnew);
                lrun[r] *= alpha;
                mrun[r] = mnew;
#pragma unroll
                for (int dj = 0; dj < 4; dj++) o[dj][r] *= alpha;
            }
        }
#pragma unroll
        for (int r = 0; r < 4; r++) {
            float psum = 0.0f;
#pragma unroll
            for (int kj = 0; kj < 8; kj++) {
                float p = exp2f(sc[kj][r] - mrun[r]);
                sc[kj][r] = p;
                psum += p;
            }
            psum += __shfl_xor(psum, 1);
            psum += __shfl_xor(psum, 2);
            psum += __shfl_xor(psum, 4);
            psum += __shfl_xor(psum, 8);
            lrun[r] += psum;
        }

        // P -> fp16 -> swizzled LDS (wave-private [16][128])
#pragma unroll
        for (int kj = 0; kj < 8; kj++)
#pragma unroll
            for (int r = 0; r < 4; r++) {
                int prow = lc * 4 + r;
                int pb = prow * 256 + (((kj * 16 + lr) * 2) ^ ((prow & 7) << 4));
                *(f16*)((char*)Pw + pb) = (f16)sc[kj][r];
            }

        // PV: O[16q x 64d] += P[16q x 128k] * V[128k x 64d]
        __builtin_amdgcn_s_setprio(1);
#pragma unroll
        for (int s2 = 0; s2 < 4; s2++) {
            f16x8 pa = *(const f16x8*)((const char*)Pw + lr * 256 + (((lc + 4 * s2) * 16) ^ psw));
#pragma unroll
            for (int dj = 0; dj < 4; dj++) {
                const int vr = dj * 16 + lr;
                f16x8 vb = *(const f16x8*)&Vs[cur][vr * 128 + 8 * ((s2 * 4 + lc) ^ (vr & 7))];
                o[dj] = __builtin_amdgcn_mfma_f32_16x16x32_f16(pa, vb, o[dj], 0, 0, 0);
            }
        }
        __builtin_amdgcn_s_setprio(0);

        asm volatile("" ::: "memory");
        __builtin_amdgcn_s_barrier();
        if (kt + 2 < nkt) {
            FSTAGE(cur, kt + 2)
            asm volatile("s_waitcnt vmcnt(8)" ::: "memory");   // tile kt+1 landed
        } else if (kt + 1 < nkt) {
            asm volatile("s_waitcnt vmcnt(0)" ::: "memory");
        }
        __builtin_amdgcn_s_barrier();
        cur ^= 1;
    }
#undef FSTAGE

#pragma unroll
    for (int dj = 0; dj < 4; dj++)
#pragma unroll
        for (int r = 0; r < 4; r++) {
            float v = o[dj][r] / lrun[r];
            attn[(size_t)(q0 + w * 16 + lc * 4 + r) * EE + h * 64 + dj * 16 + lr] = (f16)v;
        }
}

// ---------------- host launch ----------------
extern "C" void kernel_launch(void* const* d_in, const int* in_sizes, int n_in,
                              void* d_out, int out_size, void* d_ws, size_t ws_size,
                              hipStream_t stream) {
    const int*   ids  = (const int*)d_in[0];
    const float* emb  = (const float*)d_in[2];
    const float* Wq   = (const float*)d_in[3];
    const float* bq   = (const float*)d_in[4];
    const float* Wk   = (const float*)d_in[5];
    const float* bk   = (const float*)d_in[6];
    const float* Wv   = (const float*)d_in[7];
    const float* bv   = (const float*)d_in[8];
    const float* W1   = (const float*)d_in[9];
    const float* b1   = (const float*)d_in[10];
    const float* W2   = (const float*)d_in[11];
    const float* b2   = (const float*)d_in[12];
    const float* Wout = (const float*)d_in[13];
    float* out = (float*)d_out;

    char* p = (char*)d_ws;
    f16* xh    = (f16*)p; p += (size_t)SS * EE * 2;        // 4 MB
    f16* qkvh  = (f16*)p; p += (size_t)SS * 3 * EE * 2;    // 12 MB
    f16* vt    = (f16*)p; p += (size_t)EE * SS * 2;        // 4 MB
    f16* attn  = (f16*)p; p += (size_t)SS * EE * 2;        // 4 MB
    f16* h1    = (f16*)p; p += (size_t)SS * FF * 2;        // 16 MB
    f16* wqkvt = (f16*)p; p += (size_t)3 * EE * EE * 2;    // 6 MB
    f16* w1t   = (f16*)p; p += (size_t)FF * EE * 2;        // 8 MB
    f16* w2t   = (f16*)p; p += (size_t)EE * FF * 2;        // 8 MB
    f16* woutt = (f16*)p; p += (size_t)NV * EE * 2;        // 64 MB
    float* part = (float*)p; p += (size_t)4 * SS * EE * 4; // 32 MB
    float* bqkv = (float*)p; p += 3 * EE * 4;

    k_embed<<<SS, 256, 0, stream>>>(ids, emb, xh);

    for (int l = 0; l < NL; l++) {
        k_trW<<<2817, 256, 0, stream>>>(
            Wq + (size_t)l * EE * EE, Wk + (size_t)l * EE * EE, Wv + (size_t)l * EE * EE,
            W1 + (size_t)l * EE * FF, W2 + (size_t)l * FF * EE,
            bq + l * EE, bk + l * EE, bv + l * EE,
            wqkvt, w1t, w2t, bqkv);

        // QKV: [2048,1024] x [3072,1024]^T -> qkvh (Q,K) + vt (V^T). grid 8*24=192
        k_gemm<256, 128, 1><<<8 * 24, 512, 0, stream>>>(
            xh, wqkvt, bqkv, qkvh, nullptr, vt, SS, 3 * EE, EE, EE, 8, 24, 1, CS, 1.0f, 0);

        k_flash<<<dim3(NH, SS / 64), 256, 0, stream>>>(qkvh, vt, attn);

        // FFN1 + relu: grid 8*32=256
        k_gemm<256, 128, 2><<<8 * 32, 512, 0, stream>>>(
            attn, w1t, b1 + (size_t)l * FF, h1, nullptr, nullptr, SS, FF, EE, EE, 8, 32, 1, CS, 1.0f, 1);

        // FFN2 split-K=4: grid 8*8*4=256
        k_gemm<256, 128, 3><<<8 * 8 * 4, 512, 0, stream>>>(
            h1, w2t, nullptr, nullptr, part, nullptr, SS, EE, FF, FF / 4, 8, 8, 4, 0.0f, 1.0f, 0);
        k_combine4<<<SS * EE / 1024, 256, 0, stream>>>(part, b2 + (size_t)l * EE, xh);
    }

    // logits: 4-phase 256^2, grid 8*125=1000
    k_trOut<<<8000, 256, 0, stream>>>(Wout, woutt);
    k_gemm4p<<<8 * 125, 512, 0, stream>>>(xh, woutt, out, NV, EE, 8, 125, INV_CS);
}